// Round 1
// baseline (398.230 us; speedup 1.0000x reference)
//
#include <hip/hip_runtime.h>
#include <hip/hip_bf16.h>

#define B_SZ   2
#define H_SZ   48
#define W_SZ   48
#define L_SZ   2304          // H*W
#define CIN    768           // C_INNER
#define KG     4
#define DI     192           // D_IN (channels per direction)
#define NS     16            // N_STATE
#define RR     12            // R_RANK
#define XD     44            // RR + 2*NS
#define MTOK   4608          // B*L
#define CL     32            // scan chunk length
#define NC     72            // L / CL

// ---------------------------------------------------------------------------
// Generic tiled fp32 GEMM:  C[M,N] = A[M,K] * Bw[N,K]^T   (both K-contiguous)
// 64x64 tile, BK=16, 256 threads, 4x4 microtile.
// ---------------------------------------------------------------------------
__global__ __launch_bounds__(256) void gemm_nt(const float* __restrict__ A,
                                               const float* __restrict__ Bw,
                                               float* __restrict__ C,
                                               int M, int N, int K) {
    __shared__ float As[16][68];
    __shared__ float Bs[16][68];
    const int tid = threadIdx.x;
    const int bm = blockIdx.y * 64, bn = blockIdx.x * 64;
    const int tr = tid >> 4, tc = tid & 15;      // 16x16 thread grid
    const int lr = tid >> 2, lq = tid & 3;       // loader: row, quad-of-4
    float acc[4][4] = {{0.f}};

    for (int k0 = 0; k0 < K; k0 += 16) {
        float4 av = *(const float4*)&A [(size_t)(bm + lr) * K + k0 + lq * 4];
        float4 bv = *(const float4*)&Bw[(size_t)(bn + lr) * K + k0 + lq * 4];
        As[lq*4+0][lr] = av.x; As[lq*4+1][lr] = av.y;
        As[lq*4+2][lr] = av.z; As[lq*4+3][lr] = av.w;
        Bs[lq*4+0][lr] = bv.x; Bs[lq*4+1][lr] = bv.y;
        Bs[lq*4+2][lr] = bv.z; Bs[lq*4+3][lr] = bv.w;
        __syncthreads();
#pragma unroll
        for (int kk = 0; kk < 16; ++kk) {
            float4 a = *(const float4*)&As[kk][tr * 4];
            float4 b = *(const float4*)&Bs[kk][tc * 4];
            acc[0][0] += a.x*b.x; acc[0][1] += a.x*b.y; acc[0][2] += a.x*b.z; acc[0][3] += a.x*b.w;
            acc[1][0] += a.y*b.x; acc[1][1] += a.y*b.y; acc[1][2] += a.y*b.z; acc[1][3] += a.y*b.w;
            acc[2][0] += a.z*b.x; acc[2][1] += a.z*b.y; acc[2][2] += a.z*b.z; acc[2][3] += a.z*b.w;
            acc[3][0] += a.w*b.x; acc[3][1] += a.w*b.y; acc[3][2] += a.w*b.z; acc[3][3] += a.w*b.w;
        }
        __syncthreads();
    }
#pragma unroll
    for (int i = 0; i < 4; ++i) {
        float4 v = make_float4(acc[i][0], acc[i][1], acc[i][2], acc[i][3]);
        *(float4*)&C[(size_t)(bm + tr * 4 + i) * N + bn + tc * 4] = v;
    }
}

// ---------------------------------------------------------------------------
// Depthwise 3x3 conv (SAME) + bias + SiLU on NHWC input; scatter into the
// four scan orders xs[b][k][l'][d].
// ---------------------------------------------------------------------------
__global__ __launch_bounds__(256) void conv_silu_scatter(
        const float* __restrict__ xz, const float* __restrict__ cw,
        const float* __restrict__ cb, float* __restrict__ xs) {
    int idx = blockIdx.x * 256 + threadIdx.x;     // B*H*W*CIN
    int c = idx % CIN;
    int rest = idx / CIN;
    int w = rest % W_SZ; rest /= W_SZ;
    int h = rest % H_SZ;
    int b = rest / H_SZ;

    float acc = cb[c];
#pragma unroll
    for (int dh = -1; dh <= 1; ++dh) {
        int hh = h + dh;
        if (hh < 0 || hh >= H_SZ) continue;
#pragma unroll
        for (int dw = -1; dw <= 1; ++dw) {
            int ww = w + dw;
            if (ww < 0 || ww >= W_SZ) continue;
            acc += xz[(size_t)((b * H_SZ + hh) * W_SZ + ww) * CIN + c]
                 * cw[c * 9 + (dh + 1) * 3 + (dw + 1)];
        }
    }
    float s = acc / (1.f + __expf(-acc));   // SiLU

    int k = c / DI, d = c % DI;
    int lrow = h * W_SZ + w;        // row-major position
    int lcol = w * H_SZ + h;        // column-major position
    int l;
    if      (k == 0) l = lrow;
    else if (k == 1) l = lcol;
    else if (k == 2) l = L_SZ - 1 - lrow;
    else             l = L_SZ - 1 - lcol;
    xs[(size_t)((b * KG + k) * L_SZ + l) * DI + d] = s;
}

// ---------------------------------------------------------------------------
// x_dbl[bk][l][c] = sum_d xpw[k][c][d] * xs[bk][l][d]   (c = 0..43)
// ---------------------------------------------------------------------------
__global__ __launch_bounds__(256) void xproj_kernel(
        const float* __restrict__ xs, const float* __restrict__ xpw,
        float* __restrict__ xdbl) {
    int idx = blockIdx.x * 256 + threadIdx.x;     // 8*L*XD
    int c  = idx % XD;
    int l  = (idx / XD) % L_SZ;
    int bk = idx / (XD * L_SZ);
    int k  = bk % KG;
    const float4* xr = (const float4*)&xs [(size_t)(bk * L_SZ + l) * DI];
    const float4* wr = (const float4*)&xpw[(size_t)(k * XD + c) * DI];
    float acc = 0.f;
#pragma unroll 4
    for (int q = 0; q < DI / 4; ++q) {
        float4 a = xr[q], b = wr[q];
        acc += a.x * b.x + a.y * b.y + a.z * b.z + a.w * b.w;
    }
    xdbl[(size_t)(bk * L_SZ + l) * XD + c] = acc;
}

// ---------------------------------------------------------------------------
// dts[bk][l][d] = softplus( sum_r dtw[k][d][r] * xdbl[bk][l][r] + bias[k][d] )
// ---------------------------------------------------------------------------
__global__ __launch_bounds__(256) void dtproj_kernel(
        const float* __restrict__ xdbl, const float* __restrict__ dtw,
        const float* __restrict__ dtb, float* __restrict__ dts) {
    int idx = blockIdx.x * 256 + threadIdx.x;     // 8*L*DI
    int d  = idx % DI;
    int l  = (idx / DI) % L_SZ;
    int bk = idx / (DI * L_SZ);
    int k  = bk % KG;
    const float* xr = &xdbl[(size_t)(bk * L_SZ + l) * XD];
    const float* wr = &dtw[(size_t)(k * DI + d) * RR];
    float acc = dtb[k * DI + d];
#pragma unroll
    for (int r = 0; r < RR; ++r) acc += wr[r] * xr[r];
    float sp = (acc > 20.f) ? acc : log1pf(__expf(acc));
    dts[(size_t)(bk * L_SZ + l) * DI + d] = sp;
}

// ---------------------------------------------------------------------------
// Scan pass A: per (bk, chunk, d, n) compute E = prod(e_l), S = local scan.
// Block = 192 threads (lane = d). Grid = 8 * NC.
// ---------------------------------------------------------------------------
__global__ __launch_bounds__(192) void scan_passA(
        const float* __restrict__ dts, const float* __restrict__ xs,
        const float* __restrict__ xdbl, const float* __restrict__ A_logs,
        float* __restrict__ Ebuf, float* __restrict__ Sbuf) {
    int blk = blockIdx.x;
    int bk = blk / NC, ch = blk % NC;
    int d = threadIdx.x, k = bk % KG;
    int l0 = ch * CL;

    __shared__ float bsh[CL][NS];
    for (int t = threadIdx.x; t < CL * NS; t += 192) {
        int l = t / NS, n = t % NS;
        bsh[l][n] = xdbl[(size_t)(bk * L_SZ + l0 + l) * XD + RR + n];
    }
    __syncthreads();

    float Aa[NS], E[NS], S[NS];
    const float* ar = &A_logs[(size_t)(k * DI + d) * NS];
#pragma unroll
    for (int n = 0; n < NS; ++n) { Aa[n] = -__expf(ar[n]); E[n] = 1.f; S[n] = 0.f; }

    for (int l = 0; l < CL; ++l) {
        float dt = dts[(size_t)(bk * L_SZ + l0 + l) * DI + d];
        float u  = xs [(size_t)(bk * L_SZ + l0 + l) * DI + d];
        float du = dt * u;
        float4 b0 = *(const float4*)&bsh[l][0];
        float4 b1 = *(const float4*)&bsh[l][4];
        float4 b2 = *(const float4*)&bsh[l][8];
        float4 b3 = *(const float4*)&bsh[l][12];
        float Bv[NS] = {b0.x,b0.y,b0.z,b0.w, b1.x,b1.y,b1.z,b1.w,
                        b2.x,b2.y,b2.z,b2.w, b3.x,b3.y,b3.z,b3.w};
#pragma unroll
        for (int n = 0; n < NS; ++n) {
            float e = __expf(dt * Aa[n]);
            E[n] *= e;
            S[n] = fmaf(S[n], e, du * Bv[n]);
        }
    }
    float* ep = &Ebuf[(size_t)((bk * NC + ch) * DI + d) * NS];
    float* sp = &Sbuf[(size_t)((bk * NC + ch) * DI + d) * NS];
#pragma unroll
    for (int n = 0; n < NS; ++n) { ep[n] = E[n]; sp[n] = S[n]; }
}

// ---------------------------------------------------------------------------
// Scan pass B: chunk prefix. Hstart[bk][c][d][n]; h' = E*h + S over chunks.
// ---------------------------------------------------------------------------
__global__ __launch_bounds__(256) void scan_passB(
        const float* __restrict__ Ebuf, const float* __restrict__ Sbuf,
        float* __restrict__ Hstart) {
    int idx = blockIdx.x * 256 + threadIdx.x;     // 8*DI*NS = 24576
    int bk = idx / (DI * NS);
    int dn = idx % (DI * NS);
    float h = 0.f;
    for (int c = 0; c < NC; ++c) {
        size_t off = (size_t)(bk * NC + c) * DI * NS + dn;
        Hstart[off] = h;
        h = Ebuf[off] * h + Sbuf[off];
    }
}

// ---------------------------------------------------------------------------
// Scan pass C: replay chunk with true h_start, emit y into spatial layout
// ypre[b][pos][k*DI+d]  (pos = row-major h*W+w).
// ---------------------------------------------------------------------------
__global__ __launch_bounds__(192) void scan_passC(
        const float* __restrict__ dts, const float* __restrict__ xs,
        const float* __restrict__ xdbl, const float* __restrict__ A_logs,
        const float* __restrict__ Hstart, const float* __restrict__ Ds,
        float* __restrict__ ypre) {
    int blk = blockIdx.x;
    int bk = blk / NC, ch = blk % NC;
    int d = threadIdx.x, k = bk % KG, b = bk / KG;
    int l0 = ch * CL;

    __shared__ float bsh[CL][NS];
    __shared__ float csh[CL][NS];
    for (int t = threadIdx.x; t < CL * NS; t += 192) {
        int l = t / NS, n = t % NS;
        const float* row = &xdbl[(size_t)(bk * L_SZ + l0 + l) * XD];
        bsh[l][n] = row[RR + n];
        csh[l][n] = row[RR + NS + n];
    }
    __syncthreads();

    float Aa[NS], h[NS];
    const float* ar = &A_logs[(size_t)(k * DI + d) * NS];
    const float* hp = &Hstart[(size_t)((bk * NC + ch) * DI + d) * NS];
#pragma unroll
    for (int n = 0; n < NS; ++n) { Aa[n] = -__expf(ar[n]); h[n] = hp[n]; }
    float Dd = Ds[k * DI + d];

    for (int l = 0; l < CL; ++l) {
        float dt = dts[(size_t)(bk * L_SZ + l0 + l) * DI + d];
        float u  = xs [(size_t)(bk * L_SZ + l0 + l) * DI + d];
        float du = dt * u;
        float4 b0 = *(const float4*)&bsh[l][0];
        float4 b1 = *(const float4*)&bsh[l][4];
        float4 b2 = *(const float4*)&bsh[l][8];
        float4 b3 = *(const float4*)&bsh[l][12];
        float Bv[NS] = {b0.x,b0.y,b0.z,b0.w, b1.x,b1.y,b1.z,b1.w,
                        b2.x,b2.y,b2.z,b2.w, b3.x,b3.y,b3.z,b3.w};
        float4 c0 = *(const float4*)&csh[l][0];
        float4 c1 = *(const float4*)&csh[l][4];
        float4 c2 = *(const float4*)&csh[l][8];
        float4 c3 = *(const float4*)&csh[l][12];
        float Cv[NS] = {c0.x,c0.y,c0.z,c0.w, c1.x,c1.y,c1.z,c1.w,
                        c2.x,c2.y,c2.z,c2.w, c3.x,c3.y,c3.z,c3.w};
        float p[NS];
#pragma unroll
        for (int n = 0; n < NS; ++n) {
            float e = __expf(dt * Aa[n]);
            h[n] = fmaf(h[n], e, du * Bv[n]);
            p[n] = h[n] * Cv[n];
        }
        // tree sum of p[0..15]
#pragma unroll
        for (int s = 8; s >= 1; s >>= 1)
#pragma unroll
            for (int n = 0; n < 8; ++n)
                if (n < s) p[n] = p[n] + p[n + s];
        float y = fmaf(Dd, u, p[0]);

        int lg = l0 + l;
        int pos;
        if      (k == 0) pos = lg;
        else if (k == 1) pos = (lg % H_SZ) * W_SZ + (lg / H_SZ);
        else if (k == 2) pos = L_SZ - 1 - lg;
        else { int j = L_SZ - 1 - lg; pos = (j % H_SZ) * W_SZ + (j / H_SZ); }
        ypre[(size_t)(b * L_SZ + pos) * CIN + k * DI + d] = y;
    }
}

// ---------------------------------------------------------------------------
// LayerNorm over CIN=768, in place. One wave per token, 4 waves per block.
// ---------------------------------------------------------------------------
__global__ __launch_bounds__(256) void layernorm_kernel(
        float* __restrict__ y, const float* __restrict__ w,
        const float* __restrict__ bg) {
    int wave = threadIdx.x >> 6, lane = threadIdx.x & 63;
    int tok = blockIdx.x * 4 + wave;               // MTOK tokens
    float* row = &y[(size_t)tok * CIN];
    float v[12];
    float s = 0.f;
#pragma unroll
    for (int i = 0; i < 12; ++i) { v[i] = row[lane + i * 64]; s += v[i]; }
#pragma unroll
    for (int off = 32; off >= 1; off >>= 1) s += __shfl_xor(s, off, 64);
    float mu = s * (1.f / CIN);
    float s2 = 0.f;
#pragma unroll
    for (int i = 0; i < 12; ++i) { float t = v[i] - mu; s2 += t * t; }
#pragma unroll
    for (int off = 32; off >= 1; off >>= 1) s2 += __shfl_xor(s2, off, 64);
    float rstd = rsqrtf(s2 * (1.f / CIN) + 1e-5f);
#pragma unroll
    for (int i = 0; i < 12; ++i)
        row[lane + i * 64] = (v[i] - mu) * rstd * w[lane + i * 64] + bg[lane + i * 64];
}

// ---------------------------------------------------------------------------
extern "C" void kernel_launch(void* const* d_in, const int* in_sizes, int n_in,
                              void* d_out, int out_size, void* d_ws, size_t ws_size,
                              hipStream_t stream) {
    const float* x    = (const float*)d_in[0];   // (B,H,W,384)
    const float* inw  = (const float*)d_in[1];   // (768,384)
    const float* cw   = (const float*)d_in[2];   // (768,1,3,3)
    const float* cb   = (const float*)d_in[3];   // (768,)
    const float* xpw  = (const float*)d_in[4];   // (4,44,192)
    const float* dtw  = (const float*)d_in[5];   // (4,192,12)
    const float* dtb  = (const float*)d_in[6];   // (4,192)
    const float* alog = (const float*)d_in[7];   // (768,16)
    const float* Dsp  = (const float*)d_in[8];   // (768,)
    const float* lnw  = (const float*)d_in[9];   // (768,)
    const float* lnb  = (const float*)d_in[10];  // (768,)
    const float* outw = (const float*)d_in[11];  // (384,768)
    float* out = (float*)d_out;

    float* ws = (float*)d_ws;
    const size_t SZ_BIG = (size_t)MTOK * CIN;            // 3,538,944
    float* xz    = ws;                                   // 14.2 MB
    float* xs    = xz  + SZ_BIG;                         // (8,L,192)
    float* dts   = xs  + SZ_BIG;                         // (8,L,192)
    float* xdbl  = dts + SZ_BIG;                         // (8,L,44)
    float* Ebuf  = xdbl + (size_t)8 * L_SZ * XD;         // (8,NC,192,16)
    float* Sbuf  = Ebuf + (size_t)8 * NC * DI * NS;
    float* Hst   = Sbuf + (size_t)8 * NC * DI * NS;
    float* ypre  = xz;                                   // reuse: xz dead after conv

    // 1. in-proj GEMM: (4608 x 384) * (768 x 384)^T -> xz (4608 x 768)
    gemm_nt<<<dim3(CIN / 64, MTOK / 64), 256, 0, stream>>>(x, inw, xz, MTOK, CIN, 384);
    // 2. depthwise conv + SiLU + scatter into scan orders
    conv_silu_scatter<<<(B_SZ * H_SZ * W_SZ * CIN) / 256, 256, 0, stream>>>(xz, cw, cb, xs);
    // 3. x-projection (44 outputs per (bk,l))
    xproj_kernel<<<(8 * L_SZ * XD) / 256, 256, 0, stream>>>(xs, xpw, xdbl);
    // 4. dt projection + softplus
    dtproj_kernel<<<(8 * L_SZ * DI) / 256, 256, 0, stream>>>(xdbl, dtw, dtb, dts);
    // 5-7. chunked selective scan
    scan_passA<<<8 * NC, 192, 0, stream>>>(dts, xs, xdbl, alog, Ebuf, Sbuf);
    scan_passB<<<(8 * DI * NS) / 256, 256, 0, stream>>>(Ebuf, Sbuf, Hst);
    scan_passC<<<8 * NC, 192, 0, stream>>>(dts, xs, xdbl, alog, Hst, Dsp, ypre);
    // 8. LayerNorm (in place on ypre)
    layernorm_kernel<<<MTOK / 4, 256, 0, stream>>>(ypre, lnw, lnb);
    // 9. out-proj GEMM: (4608 x 768) * (384 x 768)^T -> out (4608 x 384)
    gemm_nt<<<dim3(384 / 64, MTOK / 64), 256, 0, stream>>>(ypre, outw, out, MTOK, 384, CIN);
}

// Round 2
// 342.015 us; speedup vs baseline: 1.1644x; 1.1644x over previous
//
#include <hip/hip_runtime.h>
#include <hip/hip_bf16.h>

#define B_SZ   2
#define H_SZ   48
#define W_SZ   48
#define L_SZ   2304          // H*W
#define CIN    768           // C_INNER
#define KG     4
#define DI     192           // D_IN (channels per direction)
#define NS     16            // N_STATE
#define RR     12            // R_RANK
#define XD     44            // RR + 2*NS
#define MTOK   4608          // B*L
#define CL     32            // scan chunk length
#define NC     72            // L / CL

// ---------------------------------------------------------------------------
// Generic tiled fp32 GEMM:  C[M,N] = A[M,K] * Bw[N,K]^T   (both K-contiguous)
// 64x64 tile, BK=16, 256 threads, 4x4 microtile.
// ---------------------------------------------------------------------------
__global__ __launch_bounds__(256) void gemm_nt(const float* __restrict__ A,
                                               const float* __restrict__ Bw,
                                               float* __restrict__ C,
                                               int M, int N, int K) {
    __shared__ float As[16][68];
    __shared__ float Bs[16][68];
    const int tid = threadIdx.x;
    const int bm = blockIdx.y * 64, bn = blockIdx.x * 64;
    const int tr = tid >> 4, tc = tid & 15;      // 16x16 thread grid
    const int lr = tid >> 2, lq = tid & 3;       // loader: row, quad-of-4
    float acc[4][4] = {{0.f}};

    for (int k0 = 0; k0 < K; k0 += 16) {
        float4 av = *(const float4*)&A [(size_t)(bm + lr) * K + k0 + lq * 4];
        float4 bv = *(const float4*)&Bw[(size_t)(bn + lr) * K + k0 + lq * 4];
        As[lq*4+0][lr] = av.x; As[lq*4+1][lr] = av.y;
        As[lq*4+2][lr] = av.z; As[lq*4+3][lr] = av.w;
        Bs[lq*4+0][lr] = bv.x; Bs[lq*4+1][lr] = bv.y;
        Bs[lq*4+2][lr] = bv.z; Bs[lq*4+3][lr] = bv.w;
        __syncthreads();
#pragma unroll
        for (int kk = 0; kk < 16; ++kk) {
            float4 a = *(const float4*)&As[kk][tr * 4];
            float4 b = *(const float4*)&Bs[kk][tc * 4];
            acc[0][0] += a.x*b.x; acc[0][1] += a.x*b.y; acc[0][2] += a.x*b.z; acc[0][3] += a.x*b.w;
            acc[1][0] += a.y*b.x; acc[1][1] += a.y*b.y; acc[1][2] += a.y*b.z; acc[1][3] += a.y*b.w;
            acc[2][0] += a.z*b.x; acc[2][1] += a.z*b.y; acc[2][2] += a.z*b.z; acc[2][3] += a.z*b.w;
            acc[3][0] += a.w*b.x; acc[3][1] += a.w*b.y; acc[3][2] += a.w*b.z; acc[3][3] += a.w*b.w;
        }
        __syncthreads();
    }
#pragma unroll
    for (int i = 0; i < 4; ++i) {
        float4 v = make_float4(acc[i][0], acc[i][1], acc[i][2], acc[i][3]);
        *(float4*)&C[(size_t)(bm + tr * 4 + i) * N + bn + tc * 4] = v;
    }
}

// ---------------------------------------------------------------------------
// Depthwise 3x3 conv (SAME) + bias + SiLU on NHWC input; scatter into the
// four scan orders xs[b][k][l'][d].
// ---------------------------------------------------------------------------
__global__ __launch_bounds__(256) void conv_silu_scatter(
        const float* __restrict__ xz, const float* __restrict__ cw,
        const float* __restrict__ cb, float* __restrict__ xs) {
    int idx = blockIdx.x * 256 + threadIdx.x;     // B*H*W*CIN
    int c = idx % CIN;
    int rest = idx / CIN;
    int w = rest % W_SZ; rest /= W_SZ;
    int h = rest % H_SZ;
    int b = rest / H_SZ;

    float acc = cb[c];
#pragma unroll
    for (int dh = -1; dh <= 1; ++dh) {
        int hh = h + dh;
        if (hh < 0 || hh >= H_SZ) continue;
#pragma unroll
        for (int dw = -1; dw <= 1; ++dw) {
            int ww = w + dw;
            if (ww < 0 || ww >= W_SZ) continue;
            acc += xz[(size_t)((b * H_SZ + hh) * W_SZ + ww) * CIN + c]
                 * cw[c * 9 + (dh + 1) * 3 + (dw + 1)];
        }
    }
    float s = acc / (1.f + __expf(-acc));   // SiLU

    int k = c / DI, d = c % DI;
    int lrow = h * W_SZ + w;        // row-major position
    int lcol = w * H_SZ + h;        // column-major position
    int l;
    if      (k == 0) l = lrow;
    else if (k == 1) l = lcol;
    else if (k == 2) l = L_SZ - 1 - lrow;
    else             l = L_SZ - 1 - lcol;
    xs[(size_t)((b * KG + k) * L_SZ + l) * DI + d] = s;
}

// ---------------------------------------------------------------------------
// Fused x-projection + dt-projection.
// Per block: one bk, 64 l-rows.  Stage xs^T and xpw^T tiles in LDS (BK=16),
// 4x4 microtile over (64 rows x 64 cols[44 valid]) -> x_dbl tile.
// Epilogue parks cols 0..11 in LDS; 192 threads then compute
// dts[l][d] = softplus(dot(x_dbl[l][0:12], dtw[k][d][:]) + dtb[k][d])
// with dtw held in registers and coalesced stores.
// ---------------------------------------------------------------------------
__global__ __launch_bounds__(256) void xproj_dt_kernel(
        const float* __restrict__ xs, const float* __restrict__ xpw,
        const float* __restrict__ dtw, const float* __restrict__ dtb,
        float* __restrict__ xdbl, float* __restrict__ dts) {
    __shared__ float As[16][68];
    __shared__ float Ws[16][68];
    __shared__ float dsh[64][13];

    const int tid = threadIdx.x;
    const int bm = blockIdx.x * 64;        // l-tile
    const int bk = blockIdx.y;             // 0..7
    const int k  = bk % KG;
    const int tr = tid >> 4, tc = tid & 15;
    const int lr = tid >> 2, lq = tid & 3;
    float acc[4][4] = {{0.f}};

    for (int k0 = 0; k0 < DI; k0 += 16) {
        float4 av = *(const float4*)&xs[(size_t)(bk * L_SZ + bm + lr) * DI + k0 + lq * 4];
        float4 wv = make_float4(0.f, 0.f, 0.f, 0.f);
        if (lr < XD)
            wv = *(const float4*)&xpw[(size_t)(k * XD + lr) * DI + k0 + lq * 4];
        As[lq*4+0][lr] = av.x; As[lq*4+1][lr] = av.y;
        As[lq*4+2][lr] = av.z; As[lq*4+3][lr] = av.w;
        Ws[lq*4+0][lr] = wv.x; Ws[lq*4+1][lr] = wv.y;
        Ws[lq*4+2][lr] = wv.z; Ws[lq*4+3][lr] = wv.w;
        __syncthreads();
#pragma unroll
        for (int kk = 0; kk < 16; ++kk) {
            float4 a = *(const float4*)&As[kk][tr * 4];
            float4 b = *(const float4*)&Ws[kk][tc * 4];
            acc[0][0] += a.x*b.x; acc[0][1] += a.x*b.y; acc[0][2] += a.x*b.z; acc[0][3] += a.x*b.w;
            acc[1][0] += a.y*b.x; acc[1][1] += a.y*b.y; acc[1][2] += a.y*b.z; acc[1][3] += a.y*b.w;
            acc[2][0] += a.z*b.x; acc[2][1] += a.z*b.y; acc[2][2] += a.z*b.z; acc[2][3] += a.z*b.w;
            acc[3][0] += a.w*b.x; acc[3][1] += a.w*b.y; acc[3][2] += a.w*b.z; acc[3][3] += a.w*b.w;
        }
        __syncthreads();
    }

    // epilogue: write x_dbl (c<44) and park dt-rank columns (c<12) in LDS
#pragma unroll
    for (int i = 0; i < 4; ++i) {
        if (tc < 11) {
            float4 v = make_float4(acc[i][0], acc[i][1], acc[i][2], acc[i][3]);
            *(float4*)&xdbl[(size_t)(bk * L_SZ + bm + tr * 4 + i) * XD + tc * 4] = v;
        }
        if (tc < 3) {
#pragma unroll
            for (int j = 0; j < 4; ++j)
                dsh[tr * 4 + i][tc * 4 + j] = acc[i][j];
        }
    }
    __syncthreads();

    // dt stage: one thread per d, dtw in registers, coalesced stores
    if (tid < DI) {
        const int d = tid;
        float wreg[RR];
        const float* wp = &dtw[(size_t)(k * DI + d) * RR];
#pragma unroll
        for (int r = 0; r < RR; ++r) wreg[r] = wp[r];
        const float bias = dtb[k * DI + d];
        for (int l = 0; l < 64; ++l) {
            float a = bias;
#pragma unroll
            for (int r = 0; r < RR; ++r) a = fmaf(dsh[l][r], wreg[r], a);
            float sp = (a > 20.f) ? a : log1pf(__expf(a));
            dts[(size_t)(bk * L_SZ + bm + l) * DI + d] = sp;
        }
    }
}

// ---------------------------------------------------------------------------
// Scan pass A: per (bk, chunk, d, n) compute E = prod(e_l), S = local scan.
// Block = 192 threads (lane = d). Grid = 8 * NC.
// ---------------------------------------------------------------------------
__global__ __launch_bounds__(192) void scan_passA(
        const float* __restrict__ dts, const float* __restrict__ xs,
        const float* __restrict__ xdbl, const float* __restrict__ A_logs,
        float* __restrict__ Ebuf, float* __restrict__ Sbuf) {
    int blk = blockIdx.x;
    int bk = blk / NC, ch = blk % NC;
    int d = threadIdx.x, k = bk % KG;
    int l0 = ch * CL;

    __shared__ float bsh[CL][NS];
    for (int t = threadIdx.x; t < CL * NS; t += 192) {
        int l = t / NS, n = t % NS;
        bsh[l][n] = xdbl[(size_t)(bk * L_SZ + l0 + l) * XD + RR + n];
    }
    __syncthreads();

    float Aa[NS], E[NS], S[NS];
    const float* ar = &A_logs[(size_t)(k * DI + d) * NS];
#pragma unroll
    for (int n = 0; n < NS; ++n) { Aa[n] = -__expf(ar[n]); E[n] = 1.f; S[n] = 0.f; }

    for (int l = 0; l < CL; ++l) {
        float dt = dts[(size_t)(bk * L_SZ + l0 + l) * DI + d];
        float u  = xs [(size_t)(bk * L_SZ + l0 + l) * DI + d];
        float du = dt * u;
        float4 b0 = *(const float4*)&bsh[l][0];
        float4 b1 = *(const float4*)&bsh[l][4];
        float4 b2 = *(const float4*)&bsh[l][8];
        float4 b3 = *(const float4*)&bsh[l][12];
        float Bv[NS] = {b0.x,b0.y,b0.z,b0.w, b1.x,b1.y,b1.z,b1.w,
                        b2.x,b2.y,b2.z,b2.w, b3.x,b3.y,b3.z,b3.w};
#pragma unroll
        for (int n = 0; n < NS; ++n) {
            float e = __expf(dt * Aa[n]);
            E[n] *= e;
            S[n] = fmaf(S[n], e, du * Bv[n]);
        }
    }
    float* ep = &Ebuf[(size_t)((bk * NC + ch) * DI + d) * NS];
    float* sp = &Sbuf[(size_t)((bk * NC + ch) * DI + d) * NS];
#pragma unroll
    for (int n = 0; n < NS; ++n) { ep[n] = E[n]; sp[n] = S[n]; }
}

// ---------------------------------------------------------------------------
// Scan pass B: chunk prefix. Hstart[bk][c][d][n]; h' = E*h + S over chunks.
// ---------------------------------------------------------------------------
__global__ __launch_bounds__(256) void scan_passB(
        const float* __restrict__ Ebuf, const float* __restrict__ Sbuf,
        float* __restrict__ Hstart) {
    int idx = blockIdx.x * 256 + threadIdx.x;     // 8*DI*NS = 24576
    int bk = idx / (DI * NS);
    int dn = idx % (DI * NS);
    float h = 0.f;
    for (int c = 0; c < NC; ++c) {
        size_t off = (size_t)(bk * NC + c) * DI * NS + dn;
        Hstart[off] = h;
        h = Ebuf[off] * h + Sbuf[off];
    }
}

// ---------------------------------------------------------------------------
// Scan pass C: replay chunk with true h_start, emit y into spatial layout
// ypre[b][pos][k*DI+d]  (pos = row-major h*W+w).
// ---------------------------------------------------------------------------
__global__ __launch_bounds__(192) void scan_passC(
        const float* __restrict__ dts, const float* __restrict__ xs,
        const float* __restrict__ xdbl, const float* __restrict__ A_logs,
        const float* __restrict__ Hstart, const float* __restrict__ Ds,
        float* __restrict__ ypre) {
    int blk = blockIdx.x;
    int bk = blk / NC, ch = blk % NC;
    int d = threadIdx.x, k = bk % KG, b = bk / KG;
    int l0 = ch * CL;

    __shared__ float bsh[CL][NS];
    __shared__ float csh[CL][NS];
    for (int t = threadIdx.x; t < CL * NS; t += 192) {
        int l = t / NS, n = t % NS;
        const float* row = &xdbl[(size_t)(bk * L_SZ + l0 + l) * XD];
        bsh[l][n] = row[RR + n];
        csh[l][n] = row[RR + NS + n];
    }
    __syncthreads();

    float Aa[NS], h[NS];
    const float* ar = &A_logs[(size_t)(k * DI + d) * NS];
    const float* hp = &Hstart[(size_t)((bk * NC + ch) * DI + d) * NS];
#pragma unroll
    for (int n = 0; n < NS; ++n) { Aa[n] = -__expf(ar[n]); h[n] = hp[n]; }
    float Dd = Ds[k * DI + d];

    for (int l = 0; l < CL; ++l) {
        float dt = dts[(size_t)(bk * L_SZ + l0 + l) * DI + d];
        float u  = xs [(size_t)(bk * L_SZ + l0 + l) * DI + d];
        float du = dt * u;
        float4 b0 = *(const float4*)&bsh[l][0];
        float4 b1 = *(const float4*)&bsh[l][4];
        float4 b2 = *(const float4*)&bsh[l][8];
        float4 b3 = *(const float4*)&bsh[l][12];
        float Bv[NS] = {b0.x,b0.y,b0.z,b0.w, b1.x,b1.y,b1.z,b1.w,
                        b2.x,b2.y,b2.z,b2.w, b3.x,b3.y,b3.z,b3.w};
        float4 c0 = *(const float4*)&csh[l][0];
        float4 c1 = *(const float4*)&csh[l][4];
        float4 c2 = *(const float4*)&csh[l][8];
        float4 c3 = *(const float4*)&csh[l][12];
        float Cv[NS] = {c0.x,c0.y,c0.z,c0.w, c1.x,c1.y,c1.z,c1.w,
                        c2.x,c2.y,c2.z,c2.w, c3.x,c3.y,c3.z,c3.w};
        float p[NS];
#pragma unroll
        for (int n = 0; n < NS; ++n) {
            float e = __expf(dt * Aa[n]);
            h[n] = fmaf(h[n], e, du * Bv[n]);
            p[n] = h[n] * Cv[n];
        }
        // tree sum of p[0..15]
#pragma unroll
        for (int s = 8; s >= 1; s >>= 1)
#pragma unroll
            for (int n = 0; n < 8; ++n)
                if (n < s) p[n] = p[n] + p[n + s];
        float y = fmaf(Dd, u, p[0]);

        int lg = l0 + l;
        int pos;
        if      (k == 0) pos = lg;
        else if (k == 1) pos = (lg % H_SZ) * W_SZ + (lg / H_SZ);
        else if (k == 2) pos = L_SZ - 1 - lg;
        else { int j = L_SZ - 1 - lg; pos = (j % H_SZ) * W_SZ + (j / H_SZ); }
        ypre[(size_t)(b * L_SZ + pos) * CIN + k * DI + d] = y;
    }
}

// ---------------------------------------------------------------------------
// LayerNorm over CIN=768, in place. One wave per token, 4 waves per block.
// ---------------------------------------------------------------------------
__global__ __launch_bounds__(256) void layernorm_kernel(
        float* __restrict__ y, const float* __restrict__ w,
        const float* __restrict__ bg) {
    int wave = threadIdx.x >> 6, lane = threadIdx.x & 63;
    int tok = blockIdx.x * 4 + wave;               // MTOK tokens
    float* row = &y[(size_t)tok * CIN];
    float v[12];
    float s = 0.f;
#pragma unroll
    for (int i = 0; i < 12; ++i) { v[i] = row[lane + i * 64]; s += v[i]; }
#pragma unroll
    for (int off = 32; off >= 1; off >>= 1) s += __shfl_xor(s, off, 64);
    float mu = s * (1.f / CIN);
    float s2 = 0.f;
#pragma unroll
    for (int i = 0; i < 12; ++i) { float t = v[i] - mu; s2 += t * t; }
#pragma unroll
    for (int off = 32; off >= 1; off >>= 1) s2 += __shfl_xor(s2, off, 64);
    float rstd = rsqrtf(s2 * (1.f / CIN) + 1e-5f);
#pragma unroll
    for (int i = 0; i < 12; ++i)
        row[lane + i * 64] = (v[i] - mu) * rstd * w[lane + i * 64] + bg[lane + i * 64];
}

// ---------------------------------------------------------------------------
extern "C" void kernel_launch(void* const* d_in, const int* in_sizes, int n_in,
                              void* d_out, int out_size, void* d_ws, size_t ws_size,
                              hipStream_t stream) {
    const float* x    = (const float*)d_in[0];   // (B,H,W,384)
    const float* inw  = (const float*)d_in[1];   // (768,384)
    const float* cw   = (const float*)d_in[2];   // (768,1,3,3)
    const float* cb   = (const float*)d_in[3];   // (768,)
    const float* xpw  = (const float*)d_in[4];   // (4,44,192)
    const float* dtw  = (const float*)d_in[5];   // (4,192,12)
    const float* dtb  = (const float*)d_in[6];   // (4,192)
    const float* alog = (const float*)d_in[7];   // (768,16)
    const float* Dsp  = (const float*)d_in[8];   // (768,)
    const float* lnw  = (const float*)d_in[9];   // (768,)
    const float* lnb  = (const float*)d_in[10];  // (768,)
    const float* outw = (const float*)d_in[11];  // (384,768)
    float* out = (float*)d_out;

    float* ws = (float*)d_ws;
    const size_t SZ_BIG = (size_t)MTOK * CIN;            // 3,538,944
    float* xz    = ws;                                   // 14.2 MB
    float* xs    = xz  + SZ_BIG;                         // (8,L,192)
    float* dts   = xs  + SZ_BIG;                         // (8,L,192)
    float* xdbl  = dts + SZ_BIG;                         // (8,L,44)
    float* Ebuf  = xdbl + (size_t)8 * L_SZ * XD;         // (8,NC,192,16)
    float* Sbuf  = Ebuf + (size_t)8 * NC * DI * NS;
    float* Hst   = Sbuf + (size_t)8 * NC * DI * NS;
    float* ypre  = xz;                                   // reuse: xz dead after conv

    // 1. in-proj GEMM: (4608 x 384) * (768 x 384)^T -> xz (4608 x 768)
    gemm_nt<<<dim3(CIN / 64, MTOK / 64), 256, 0, stream>>>(x, inw, xz, MTOK, CIN, 384);
    // 2. depthwise conv + SiLU + scatter into scan orders
    conv_silu_scatter<<<(B_SZ * H_SZ * W_SZ * CIN) / 256, 256, 0, stream>>>(xz, cw, cb, xs);
    // 3+4. fused x-projection + dt-projection
    xproj_dt_kernel<<<dim3(L_SZ / 64, 8), 256, 0, stream>>>(xs, xpw, dtw, dtb, xdbl, dts);
    // 5-7. chunked selective scan
    scan_passA<<<8 * NC, 192, 0, stream>>>(dts, xs, xdbl, alog, Ebuf, Sbuf);
    scan_passB<<<(8 * DI * NS) / 256, 256, 0, stream>>>(Ebuf, Sbuf, Hst);
    scan_passC<<<8 * NC, 192, 0, stream>>>(dts, xs, xdbl, alog, Hst, Dsp, ypre);
    // 8. LayerNorm (in place on ypre)
    layernorm_kernel<<<MTOK / 4, 256, 0, stream>>>(ypre, lnw, lnb);
    // 9. out-proj GEMM: (4608 x 768) * (384 x 768)^T -> out (4608 x 384)
    gemm_nt<<<dim3(384 / 64, MTOK / 64), 256, 0, stream>>>(ypre, outw, out, MTOK, 384, CIN);
}

// Round 3
// 269.793 us; speedup vs baseline: 1.4761x; 1.2677x over previous
//
#include <hip/hip_runtime.h>
#include <hip/hip_bf16.h>

#define B_SZ   2
#define H_SZ   48
#define W_SZ   48
#define L_SZ   2304          // H*W
#define CIN    768           // C_INNER
#define KG     4
#define DI     192           // D_IN (channels per direction)
#define NS     16            // N_STATE
#define RR     12            // R_RANK
#define XD     44            // RR + 2*NS
#define MTOK   4608          // B*L
#define CL     32            // scan chunk length
#define NC     72            // L / CL

typedef __attribute__((ext_vector_type(8))) short short8;
typedef __attribute__((ext_vector_type(4))) float f32x4;

__device__ inline ushort f2b(float f) {
    uint u = __builtin_bit_cast(uint, f);
    u = (u + 0x7FFF + ((u >> 16) & 1)) >> 16;   // RNE to bf16
    return (ushort)u;
}

// ---------------------------------------------------------------------------
// bf16 MFMA GEMM:  C[M,N](fp32) = A[M,K](bf16) * Bw[N,K](bf16)^T
// 128x128 tile, BK=32, 256 threads (4 waves in 2x2), 4x4 frags of 16x16x32.
// ---------------------------------------------------------------------------
__global__ __launch_bounds__(256) void gemm_bf16_nt(
        const ushort* __restrict__ A, const ushort* __restrict__ Bw,
        float* __restrict__ C, int M, int N, int K) {
    __shared__ ushort As[128][40];   // pad 32 -> 40 (+16B) to spread banks
    __shared__ ushort Bs[128][40];
    const int tid  = threadIdx.x;
    const int lane = tid & 63;
    const int wave = tid >> 6;
    const int wr = (wave >> 1) * 64;      // wave M-quadrant
    const int wc = (wave & 1) * 64;       // wave N-quadrant
    const int bm = blockIdx.y * 128, bn = blockIdx.x * 128;
    const int lrow = tid >> 1;            // loader row 0..127
    const int lcol = (tid & 1) * 16;      // loader k-offset 0/16
    const int frow = lane & 15;           // fragment row within 16
    const int fk   = (lane >> 4) * 8;     // fragment k offset (quad*8)

    f32x4 acc[4][4] = {};

    for (int k0 = 0; k0 < K; k0 += 32) {
        const ushort* ap = &A [(size_t)(bm + lrow) * K + k0 + lcol];
        const ushort* bp = &Bw[(size_t)(bn + lrow) * K + k0 + lcol];
        float4 a0 = *(const float4*)ap;
        float4 a1 = *(const float4*)(ap + 8);
        float4 b0 = *(const float4*)bp;
        float4 b1 = *(const float4*)(bp + 8);
        __syncthreads();                    // protect prior iter's reads
        *(float4*)&As[lrow][lcol]     = a0;
        *(float4*)&As[lrow][lcol + 8] = a1;
        *(float4*)&Bs[lrow][lcol]     = b0;
        *(float4*)&Bs[lrow][lcol + 8] = b1;
        __syncthreads();

        short8 af[4], bf[4];
#pragma unroll
        for (int i = 0; i < 4; ++i) {
            af[i] = *(const short8*)&As[wr + i * 16 + frow][fk];
            bf[i] = *(const short8*)&Bs[wc + i * 16 + frow][fk];
        }
#pragma unroll
        for (int mi = 0; mi < 4; ++mi)
#pragma unroll
            for (int ni = 0; ni < 4; ++ni)
                acc[mi][ni] = __builtin_amdgcn_mfma_f32_16x16x32_bf16(
                                  af[mi], bf[ni], acc[mi][ni], 0, 0, 0);
    }

#pragma unroll
    for (int mi = 0; mi < 4; ++mi) {
        int rbase = bm + wr + mi * 16 + (lane >> 4) * 4;
#pragma unroll
        for (int ni = 0; ni < 4; ++ni) {
            int col = bn + wc + ni * 16 + (lane & 15);
#pragma unroll
            for (int r = 0; r < 4; ++r)
                C[(size_t)(rbase + r) * N + col] = acc[mi][ni][r];
        }
    }
}

// ---------------------------------------------------------------------------
// Cast x, in_proj_w, out_proj_w to bf16 in one launch. 8 elems/thread.
// ---------------------------------------------------------------------------
#define NX8 (MTOK * 384 / 8)      // 221184
#define NW8 (CIN * 384 / 8)       // 36864
__global__ __launch_bounds__(256) void cast_bf16_3(
        const float* __restrict__ x, const float* __restrict__ w1,
        const float* __restrict__ w2, ushort* __restrict__ xb,
        ushort* __restrict__ w1b, ushort* __restrict__ w2b) {
    int t = blockIdx.x * 256 + threadIdx.x;      // 294912 threads total
    const float* src; ushort* dst; int off;
    if (t < NX8)            { src = x;  dst = xb;  off = t; }
    else if (t < NX8 + NW8) { src = w1; dst = w1b; off = t - NX8; }
    else                    { src = w2; dst = w2b; off = t - NX8 - NW8; }
    float4 v0 = ((const float4*)src)[off * 2];
    float4 v1 = ((const float4*)src)[off * 2 + 1];
    ushort u[8] = { f2b(v0.x), f2b(v0.y), f2b(v0.z), f2b(v0.w),
                    f2b(v1.x), f2b(v1.y), f2b(v1.z), f2b(v1.w) };
    *(float4*)&dst[off * 8] = *(float4*)u;
}

// ---------------------------------------------------------------------------
// Depthwise 3x3 conv (SAME) + bias + SiLU on NHWC input; scatter into the
// four scan orders xs[b][k][l'][d].
// ---------------------------------------------------------------------------
__global__ __launch_bounds__(256) void conv_silu_scatter(
        const float* __restrict__ xz, const float* __restrict__ cw,
        const float* __restrict__ cb, float* __restrict__ xs) {
    int idx = blockIdx.x * 256 + threadIdx.x;     // B*H*W*CIN
    int c = idx % CIN;
    int rest = idx / CIN;
    int w = rest % W_SZ; rest /= W_SZ;
    int h = rest % H_SZ;
    int b = rest / H_SZ;

    float acc = cb[c];
#pragma unroll
    for (int dh = -1; dh <= 1; ++dh) {
        int hh = h + dh;
        if (hh < 0 || hh >= H_SZ) continue;
#pragma unroll
        for (int dw = -1; dw <= 1; ++dw) {
            int ww = w + dw;
            if (ww < 0 || ww >= W_SZ) continue;
            acc += xz[(size_t)((b * H_SZ + hh) * W_SZ + ww) * CIN + c]
                 * cw[c * 9 + (dh + 1) * 3 + (dw + 1)];
        }
    }
    float s = acc / (1.f + __expf(-acc));   // SiLU

    int k = c / DI, d = c % DI;
    int lrow = h * W_SZ + w;        // row-major position
    int lcol = w * H_SZ + h;        // column-major position
    int l;
    if      (k == 0) l = lrow;
    else if (k == 1) l = lcol;
    else if (k == 2) l = L_SZ - 1 - lrow;
    else             l = L_SZ - 1 - lcol;
    xs[(size_t)((b * KG + k) * L_SZ + l) * DI + d] = s;
}

// ---------------------------------------------------------------------------
// Fused x-projection + dt-projection (fp32 tiled GEMM, N=44 small).
// ---------------------------------------------------------------------------
__global__ __launch_bounds__(256) void xproj_dt_kernel(
        const float* __restrict__ xs, const float* __restrict__ xpw,
        const float* __restrict__ dtw, const float* __restrict__ dtb,
        float* __restrict__ xdbl, float* __restrict__ dts) {
    __shared__ float As[16][68];
    __shared__ float Ws[16][68];
    __shared__ float dsh[64][13];

    const int tid = threadIdx.x;
    const int bm = blockIdx.x * 64;        // l-tile
    const int bk = blockIdx.y;             // 0..7
    const int k  = bk % KG;
    const int tr = tid >> 4, tc = tid & 15;
    const int lr = tid >> 2, lq = tid & 3;
    float acc[4][4] = {{0.f}};

    for (int k0 = 0; k0 < DI; k0 += 16) {
        float4 av = *(const float4*)&xs[(size_t)(bk * L_SZ + bm + lr) * DI + k0 + lq * 4];
        float4 wv = make_float4(0.f, 0.f, 0.f, 0.f);
        if (lr < XD)
            wv = *(const float4*)&xpw[(size_t)(k * XD + lr) * DI + k0 + lq * 4];
        As[lq*4+0][lr] = av.x; As[lq*4+1][lr] = av.y;
        As[lq*4+2][lr] = av.z; As[lq*4+3][lr] = av.w;
        Ws[lq*4+0][lr] = wv.x; Ws[lq*4+1][lr] = wv.y;
        Ws[lq*4+2][lr] = wv.z; Ws[lq*4+3][lr] = wv.w;
        __syncthreads();
#pragma unroll
        for (int kk = 0; kk < 16; ++kk) {
            float4 a = *(const float4*)&As[kk][tr * 4];
            float4 b = *(const float4*)&Ws[kk][tc * 4];
            acc[0][0] += a.x*b.x; acc[0][1] += a.x*b.y; acc[0][2] += a.x*b.z; acc[0][3] += a.x*b.w;
            acc[1][0] += a.y*b.x; acc[1][1] += a.y*b.y; acc[1][2] += a.y*b.z; acc[1][3] += a.y*b.w;
            acc[2][0] += a.z*b.x; acc[2][1] += a.z*b.y; acc[2][2] += a.z*b.z; acc[2][3] += a.z*b.w;
            acc[3][0] += a.w*b.x; acc[3][1] += a.w*b.y; acc[3][2] += a.w*b.z; acc[3][3] += a.w*b.w;
        }
        __syncthreads();
    }

#pragma unroll
    for (int i = 0; i < 4; ++i) {
        if (tc < 11) {
            float4 v = make_float4(acc[i][0], acc[i][1], acc[i][2], acc[i][3]);
            *(float4*)&xdbl[(size_t)(bk * L_SZ + bm + tr * 4 + i) * XD + tc * 4] = v;
        }
        if (tc < 3) {
#pragma unroll
            for (int j = 0; j < 4; ++j)
                dsh[tr * 4 + i][tc * 4 + j] = acc[i][j];
        }
    }
    __syncthreads();

    if (tid < DI) {
        const int d = tid;
        float wreg[RR];
        const float* wp = &dtw[(size_t)(k * DI + d) * RR];
#pragma unroll
        for (int r = 0; r < RR; ++r) wreg[r] = wp[r];
        const float bias = dtb[k * DI + d];
        for (int l = 0; l < 64; ++l) {
            float a = bias;
#pragma unroll
            for (int r = 0; r < RR; ++r) a = fmaf(dsh[l][r], wreg[r], a);
            float sp = (a > 20.f) ? a : log1pf(__expf(a));
            dts[(size_t)(bk * L_SZ + bm + l) * DI + d] = sp;
        }
    }
}

// ---------------------------------------------------------------------------
// Scan pass A
// ---------------------------------------------------------------------------
__global__ __launch_bounds__(192) void scan_passA(
        const float* __restrict__ dts, const float* __restrict__ xs,
        const float* __restrict__ xdbl, const float* __restrict__ A_logs,
        float* __restrict__ Ebuf, float* __restrict__ Sbuf) {
    int blk = blockIdx.x;
    int bk = blk / NC, ch = blk % NC;
    int d = threadIdx.x, k = bk % KG;
    int l0 = ch * CL;

    __shared__ float bsh[CL][NS];
    for (int t = threadIdx.x; t < CL * NS; t += 192) {
        int l = t / NS, n = t % NS;
        bsh[l][n] = xdbl[(size_t)(bk * L_SZ + l0 + l) * XD + RR + n];
    }
    __syncthreads();

    float Aa[NS], E[NS], S[NS];
    const float* ar = &A_logs[(size_t)(k * DI + d) * NS];
#pragma unroll
    for (int n = 0; n < NS; ++n) { Aa[n] = -__expf(ar[n]); E[n] = 1.f; S[n] = 0.f; }

    for (int l = 0; l < CL; ++l) {
        float dt = dts[(size_t)(bk * L_SZ + l0 + l) * DI + d];
        float u  = xs [(size_t)(bk * L_SZ + l0 + l) * DI + d];
        float du = dt * u;
        float4 b0 = *(const float4*)&bsh[l][0];
        float4 b1 = *(const float4*)&bsh[l][4];
        float4 b2 = *(const float4*)&bsh[l][8];
        float4 b3 = *(const float4*)&bsh[l][12];
        float Bv[NS] = {b0.x,b0.y,b0.z,b0.w, b1.x,b1.y,b1.z,b1.w,
                        b2.x,b2.y,b2.z,b2.w, b3.x,b3.y,b3.z,b3.w};
#pragma unroll
        for (int n = 0; n < NS; ++n) {
            float e = __expf(dt * Aa[n]);
            E[n] *= e;
            S[n] = fmaf(S[n], e, du * Bv[n]);
        }
    }
    float* ep = &Ebuf[(size_t)((bk * NC + ch) * DI + d) * NS];
    float* sp = &Sbuf[(size_t)((bk * NC + ch) * DI + d) * NS];
#pragma unroll
    for (int n = 0; n < NS; ++n) { ep[n] = E[n]; sp[n] = S[n]; }
}

// ---------------------------------------------------------------------------
// Scan pass B: chunk prefix
// ---------------------------------------------------------------------------
__global__ __launch_bounds__(256) void scan_passB(
        const float* __restrict__ Ebuf, const float* __restrict__ Sbuf,
        float* __restrict__ Hstart) {
    int idx = blockIdx.x * 256 + threadIdx.x;     // 8*DI*NS = 24576
    int bk = idx / (DI * NS);
    int dn = idx % (DI * NS);
    float h = 0.f;
    for (int c = 0; c < NC; ++c) {
        size_t off = (size_t)(bk * NC + c) * DI * NS + dn;
        Hstart[off] = h;
        h = Ebuf[off] * h + Sbuf[off];
    }
}

// ---------------------------------------------------------------------------
// Scan pass C: replay chunk, emit y into spatial layout
// ---------------------------------------------------------------------------
__global__ __launch_bounds__(192) void scan_passC(
        const float* __restrict__ dts, const float* __restrict__ xs,
        const float* __restrict__ xdbl, const float* __restrict__ A_logs,
        const float* __restrict__ Hstart, const float* __restrict__ Ds,
        float* __restrict__ ypre) {
    int blk = blockIdx.x;
    int bk = blk / NC, ch = blk % NC;
    int d = threadIdx.x, k = bk % KG, b = bk / KG;
    int l0 = ch * CL;

    __shared__ float bsh[CL][NS];
    __shared__ float csh[CL][NS];
    for (int t = threadIdx.x; t < CL * NS; t += 192) {
        int l = t / NS, n = t % NS;
        const float* row = &xdbl[(size_t)(bk * L_SZ + l0 + l) * XD];
        bsh[l][n] = row[RR + n];
        csh[l][n] = row[RR + NS + n];
    }
    __syncthreads();

    float Aa[NS], h[NS];
    const float* ar = &A_logs[(size_t)(k * DI + d) * NS];
    const float* hp = &Hstart[(size_t)((bk * NC + ch) * DI + d) * NS];
#pragma unroll
    for (int n = 0; n < NS; ++n) { Aa[n] = -__expf(ar[n]); h[n] = hp[n]; }
    float Dd = Ds[k * DI + d];

    for (int l = 0; l < CL; ++l) {
        float dt = dts[(size_t)(bk * L_SZ + l0 + l) * DI + d];
        float u  = xs [(size_t)(bk * L_SZ + l0 + l) * DI + d];
        float du = dt * u;
        float4 b0 = *(const float4*)&bsh[l][0];
        float4 b1 = *(const float4*)&bsh[l][4];
        float4 b2 = *(const float4*)&bsh[l][8];
        float4 b3 = *(const float4*)&bsh[l][12];
        float Bv[NS] = {b0.x,b0.y,b0.z,b0.w, b1.x,b1.y,b1.z,b1.w,
                        b2.x,b2.y,b2.z,b2.w, b3.x,b3.y,b3.z,b3.w};
        float4 c0 = *(const float4*)&csh[l][0];
        float4 c1 = *(const float4*)&csh[l][4];
        float4 c2 = *(const float4*)&csh[l][8];
        float4 c3 = *(const float4*)&csh[l][12];
        float Cv[NS] = {c0.x,c0.y,c0.z,c0.w, c1.x,c1.y,c1.z,c1.w,
                        c2.x,c2.y,c2.z,c2.w, c3.x,c3.y,c3.z,c3.w};
        float p[NS];
#pragma unroll
        for (int n = 0; n < NS; ++n) {
            float e = __expf(dt * Aa[n]);
            h[n] = fmaf(h[n], e, du * Bv[n]);
            p[n] = h[n] * Cv[n];
        }
#pragma unroll
        for (int s = 8; s >= 1; s >>= 1)
#pragma unroll
            for (int n = 0; n < 8; ++n)
                if (n < s) p[n] = p[n] + p[n + s];
        float y = fmaf(Dd, u, p[0]);

        int lg = l0 + l;
        int pos;
        if      (k == 0) pos = lg;
        else if (k == 1) pos = (lg % H_SZ) * W_SZ + (lg / H_SZ);
        else if (k == 2) pos = L_SZ - 1 - lg;
        else { int j = L_SZ - 1 - lg; pos = (j % H_SZ) * W_SZ + (j / H_SZ); }
        ypre[(size_t)(b * L_SZ + pos) * CIN + k * DI + d] = y;
    }
}

// ---------------------------------------------------------------------------
// LayerNorm over CIN=768; read fp32, write bf16 (for out-proj MFMA).
// ---------------------------------------------------------------------------
__global__ __launch_bounds__(256) void layernorm_bf16(
        const float* __restrict__ y, ushort* __restrict__ yb,
        const float* __restrict__ w, const float* __restrict__ bg) {
    int wave = threadIdx.x >> 6, lane = threadIdx.x & 63;
    int tok = blockIdx.x * 4 + wave;               // MTOK tokens
    const float* row = &y[(size_t)tok * CIN];
    ushort* rowo = &yb[(size_t)tok * CIN];
    float v[12];
    float s = 0.f;
#pragma unroll
    for (int i = 0; i < 12; ++i) { v[i] = row[lane + i * 64]; s += v[i]; }
#pragma unroll
    for (int off = 32; off >= 1; off >>= 1) s += __shfl_xor(s, off, 64);
    float mu = s * (1.f / CIN);
    float s2 = 0.f;
#pragma unroll
    for (int i = 0; i < 12; ++i) { float t = v[i] - mu; s2 += t * t; }
#pragma unroll
    for (int off = 32; off >= 1; off >>= 1) s2 += __shfl_xor(s2, off, 64);
    float rstd = rsqrtf(s2 * (1.f / CIN) + 1e-5f);
#pragma unroll
    for (int i = 0; i < 12; ++i)
        rowo[lane + i * 64] =
            f2b((v[i] - mu) * rstd * w[lane + i * 64] + bg[lane + i * 64]);
}

// ---------------------------------------------------------------------------
extern "C" void kernel_launch(void* const* d_in, const int* in_sizes, int n_in,
                              void* d_out, int out_size, void* d_ws, size_t ws_size,
                              hipStream_t stream) {
    const float* x    = (const float*)d_in[0];   // (B,H,W,384)
    const float* inw  = (const float*)d_in[1];   // (768,384)
    const float* cw   = (const float*)d_in[2];   // (768,1,3,3)
    const float* cb   = (const float*)d_in[3];   // (768,)
    const float* xpw  = (const float*)d_in[4];   // (4,44,192)
    const float* dtw  = (const float*)d_in[5];   // (4,192,12)
    const float* dtb  = (const float*)d_in[6];   // (4,192)
    const float* alog = (const float*)d_in[7];   // (768,16)
    const float* Dsp  = (const float*)d_in[8];   // (768,)
    const float* lnw  = (const float*)d_in[9];   // (768,)
    const float* lnb  = (const float*)d_in[10];  // (768,)
    const float* outw = (const float*)d_in[11];  // (384,768)
    float* out = (float*)d_out;

    float* ws = (float*)d_ws;
    const size_t SZ_BIG = (size_t)MTOK * CIN;            // 3,538,944
    float* xz    = ws;                                   // 14.2 MB; later ypre
    float* xs    = xz  + SZ_BIG;
    float* dts   = xs  + SZ_BIG;
    float* xdbl  = dts + SZ_BIG;                         // (8,L,44)
    float* Ebuf  = xdbl + (size_t)8 * L_SZ * XD;         // (8,NC,192,16)
    float* Sbuf  = Ebuf + (size_t)8 * NC * DI * NS;
    float* Hst   = Sbuf + (size_t)8 * NC * DI * NS;
    ushort* outwb = (ushort*)(Hst + (size_t)8 * NC * DI * NS);  // +0.59 MB
    // lifetime overlays:
    ushort* xb     = (ushort*)dts;    // cast -> in-proj GEMM (dts written later)
    ushort* inwb   = (ushort*)Ebuf;   // cast -> in-proj GEMM (Ebuf written later)
    ushort* ypre_b = (ushort*)Sbuf;   // LN -> out-proj (Sbuf dead after passB)
    float*  ypre   = xz;              // passC output (xz dead after conv)

    // 0. cast x, in_proj_w, out_proj_w to bf16
    cast_bf16_3<<<(NX8 + 2 * NW8) / 256, 256, 0, stream>>>(x, inw, outw, xb, inwb, outwb);
    // 1. in-proj GEMM (bf16 MFMA): (4608x384)*(768x384)^T -> xz fp32
    gemm_bf16_nt<<<dim3(CIN / 128, MTOK / 128), 256, 0, stream>>>(xb, inwb, xz, MTOK, CIN, 384);
    // 2. depthwise conv + SiLU + scatter into scan orders
    conv_silu_scatter<<<(B_SZ * H_SZ * W_SZ * CIN) / 256, 256, 0, stream>>>(xz, cw, cb, xs);
    // 3+4. fused x-projection + dt-projection
    xproj_dt_kernel<<<dim3(L_SZ / 64, 8), 256, 0, stream>>>(xs, xpw, dtw, dtb, xdbl, dts);
    // 5-7. chunked selective scan
    scan_passA<<<8 * NC, 192, 0, stream>>>(dts, xs, xdbl, alog, Ebuf, Sbuf);
    scan_passB<<<(8 * DI * NS) / 256, 256, 0, stream>>>(Ebuf, Sbuf, Hst);
    scan_passC<<<8 * NC, 192, 0, stream>>>(dts, xs, xdbl, alog, Hst, Dsp, ypre);
    // 8. LayerNorm: fp32 in, bf16 out
    layernorm_bf16<<<MTOK / 4, 256, 0, stream>>>(ypre, ypre_b, lnw, lnb);
    // 9. out-proj GEMM (bf16 MFMA): (4608x768)*(384x768)^T -> out fp32
    gemm_bf16_nt<<<dim3(384 / 128, MTOK / 128), 256, 0, stream>>>(ypre_b, outwb, out, MTOK, 384, CIN);
}

// Round 4
// 253.560 us; speedup vs baseline: 1.5706x; 1.0640x over previous
//
#include <hip/hip_runtime.h>
#include <hip/hip_bf16.h>

#define B_SZ   2
#define H_SZ   48
#define W_SZ   48
#define L_SZ   2304          // H*W
#define CIN    768           // C_INNER
#define KG     4
#define DI     192           // D_IN (channels per direction)
#define NS     16            // N_STATE
#define RR     12            // R_RANK
#define XD     44            // RR + 2*NS
#define MTOK   4608          // B*L
#define CL     32            // scan chunk length
#define NC     72            // L / CL

typedef __attribute__((ext_vector_type(8))) short short8;
typedef __attribute__((ext_vector_type(4))) float f32x4;

__device__ inline ushort f2b(float f) {
    uint u = __builtin_bit_cast(uint, f);
    u = (u + 0x7FFF + ((u >> 16) & 1)) >> 16;   // RNE to bf16
    return (ushort)u;
}

// ---------------------------------------------------------------------------
// bf16 MFMA GEMM:  C[M,N](fp32) = A[M,K](bf16) * Bw[N,K](bf16)^T
// 128x128 tile, BK=32, 256 threads (4 waves in 2x2), 4x4 frags of 16x16x32.
// ---------------------------------------------------------------------------
__global__ __launch_bounds__(256) void gemm_bf16_nt(
        const ushort* __restrict__ A, const ushort* __restrict__ Bw,
        float* __restrict__ C, int M, int N, int K) {
    __shared__ ushort As[128][40];
    __shared__ ushort Bs[128][40];
    const int tid  = threadIdx.x;
    const int lane = tid & 63;
    const int wave = tid >> 6;
    const int wr = (wave >> 1) * 64;      // wave M-quadrant
    const int wc = (wave & 1) * 64;       // wave N-quadrant
    const int bm = blockIdx.y * 128, bn = blockIdx.x * 128;
    const int lrow = tid >> 1;            // loader row 0..127
    const int lcol = (tid & 1) * 16;      // loader k-offset 0/16
    const int frow = lane & 15;
    const int fk   = (lane >> 4) * 8;

    f32x4 acc[4][4] = {};

    for (int k0 = 0; k0 < K; k0 += 32) {
        const ushort* ap = &A [(size_t)(bm + lrow) * K + k0 + lcol];
        const ushort* bp = &Bw[(size_t)(bn + lrow) * K + k0 + lcol];
        float4 a0 = *(const float4*)ap;
        float4 a1 = *(const float4*)(ap + 8);
        float4 b0 = *(const float4*)bp;
        float4 b1 = *(const float4*)(bp + 8);
        __syncthreads();
        *(float4*)&As[lrow][lcol]     = a0;
        *(float4*)&As[lrow][lcol + 8] = a1;
        *(float4*)&Bs[lrow][lcol]     = b0;
        *(float4*)&Bs[lrow][lcol + 8] = b1;
        __syncthreads();

        short8 af[4], bf[4];
#pragma unroll
        for (int i = 0; i < 4; ++i) {
            af[i] = *(const short8*)&As[wr + i * 16 + frow][fk];
            bf[i] = *(const short8*)&Bs[wc + i * 16 + frow][fk];
        }
#pragma unroll
        for (int mi = 0; mi < 4; ++mi)
#pragma unroll
            for (int ni = 0; ni < 4; ++ni)
                acc[mi][ni] = __builtin_amdgcn_mfma_f32_16x16x32_bf16(
                                  af[mi], bf[ni], acc[mi][ni], 0, 0, 0);
    }

#pragma unroll
    for (int mi = 0; mi < 4; ++mi) {
        int rbase = bm + wr + mi * 16 + (lane >> 4) * 4;
#pragma unroll
        for (int ni = 0; ni < 4; ++ni) {
            int col = bn + wc + ni * 16 + (lane & 15);
#pragma unroll
            for (int r = 0; r < 4; ++r)
                C[(size_t)(rbase + r) * N + col] = acc[mi][ni][r];
        }
    }
}

// ---------------------------------------------------------------------------
// Cast kernel: x, in_proj_w, out_proj_w -> bf16; xpw -> padded bf16 [4][48][192];
// dtw -> padded bf16 [4][192][40] (cols 12..39 zero).
// ---------------------------------------------------------------------------
#define NX8 (MTOK * 384 / 8)      // 221184
#define NW8 (CIN * 384 / 8)       // 36864
#define NP8 (4 * 48 * 192 / 8)    // 4608
#define ND8 (4 * DI * 40 / 8)     // 3840
__global__ __launch_bounds__(256) void cast_bf16_all(
        const float* __restrict__ x, const float* __restrict__ w1,
        const float* __restrict__ w2, const float* __restrict__ xpw,
        const float* __restrict__ dtw,
        ushort* __restrict__ xb, ushort* __restrict__ w1b,
        ushort* __restrict__ w2b, ushort* __restrict__ xpwb,
        ushort* __restrict__ dtwb) {
    int t = blockIdx.x * 256 + threadIdx.x;
    if (t < NX8 + 2 * NW8) {
        const float* src; ushort* dst; int off;
        if (t < NX8)            { src = x;  dst = xb;  off = t; }
        else if (t < NX8 + NW8) { src = w1; dst = w1b; off = t - NX8; }
        else                    { src = w2; dst = w2b; off = t - NX8 - NW8; }
        float4 v0 = ((const float4*)src)[off * 2];
        float4 v1 = ((const float4*)src)[off * 2 + 1];
        ushort u[8] = { f2b(v0.x), f2b(v0.y), f2b(v0.z), f2b(v0.w),
                        f2b(v1.x), f2b(v1.y), f2b(v1.z), f2b(v1.w) };
        *(float4*)&dst[off * 8] = *(float4*)u;
    } else if (t < NX8 + 2 * NW8 + NP8) {
        int e0 = (t - NX8 - 2 * NW8) * 8;
        int kk = e0 / (48 * 192);
        int rem = e0 % (48 * 192);
        int c = rem / 192, col = rem % 192;
        ushort u[8] = {0,0,0,0,0,0,0,0};
        if (c < XD) {
            const float* src = &xpw[((size_t)kk * XD + c) * 192 + col];
            float4 v0 = *(const float4*)src;
            float4 v1 = *(const float4*)(src + 4);
            u[0]=f2b(v0.x); u[1]=f2b(v0.y); u[2]=f2b(v0.z); u[3]=f2b(v0.w);
            u[4]=f2b(v1.x); u[5]=f2b(v1.y); u[6]=f2b(v1.z); u[7]=f2b(v1.w);
        }
        *(float4*)&xpwb[e0] = *(float4*)u;
    } else if (t < NX8 + 2 * NW8 + NP8 + ND8) {
        int e0 = (t - NX8 - 2 * NW8 - NP8) * 8;
        int row = e0 / 40, c0 = e0 % 40;          // c0 in {0,8,16,24,32}
        ushort u[8] = {0,0,0,0,0,0,0,0};
        if (c0 < RR) {
#pragma unroll
            for (int j = 0; j < 8; ++j) {
                int col = c0 + j;
                if (col < RR) u[j] = f2b(dtw[(size_t)row * RR + col]);
            }
        }
        *(float4*)&dtwb[e0] = *(float4*)u;
    }
}

// ---------------------------------------------------------------------------
// Depthwise 3x3 conv (SAME) + bias + SiLU on NHWC input; scatter into the
// four scan orders xs[b][k][l'][d] (fp32) and xsb (bf16, for MFMA xproj).
// ---------------------------------------------------------------------------
__global__ __launch_bounds__(256) void conv_silu_scatter(
        const float* __restrict__ xz, const float* __restrict__ cw,
        const float* __restrict__ cb, float* __restrict__ xs,
        ushort* __restrict__ xsb) {
    int idx = blockIdx.x * 256 + threadIdx.x;     // B*H*W*CIN
    int c = idx % CIN;
    int rest = idx / CIN;
    int w = rest % W_SZ; rest /= W_SZ;
    int h = rest % H_SZ;
    int b = rest / H_SZ;

    float acc = cb[c];
#pragma unroll
    for (int dh = -1; dh <= 1; ++dh) {
        int hh = h + dh;
        if (hh < 0 || hh >= H_SZ) continue;
#pragma unroll
        for (int dw = -1; dw <= 1; ++dw) {
            int ww = w + dw;
            if (ww < 0 || ww >= W_SZ) continue;
            acc += xz[(size_t)((b * H_SZ + hh) * W_SZ + ww) * CIN + c]
                 * cw[c * 9 + (dh + 1) * 3 + (dw + 1)];
        }
    }
    float s = acc / (1.f + __expf(-acc));   // SiLU

    int k = c / DI, d = c % DI;
    int lrow = h * W_SZ + w;
    int lcol = w * H_SZ + h;
    int l;
    if      (k == 0) l = lrow;
    else if (k == 1) l = lcol;
    else if (k == 2) l = L_SZ - 1 - lrow;
    else             l = L_SZ - 1 - lcol;
    size_t o = (size_t)((b * KG + k) * L_SZ + l) * DI + d;
    xs[o]  = s;
    xsb[o] = f2b(s);
}

// ---------------------------------------------------------------------------
// MFMA fused x-projection + dt-projection.
// Block: 64 l-rows of one bk. GEMM1: (64x192)x(48x192)^T -> x_dbl tile
// (cols 12..43 -> xdbl global, cols 0..11 -> LDS bf16 padded K=32).
// GEMM2: (64x32)x(192x32)^T -> softplus -> dts.
// ---------------------------------------------------------------------------
__global__ __launch_bounds__(256) void xproj_dt_mfma(
        const ushort* __restrict__ xsb, const ushort* __restrict__ xpwb,
        const ushort* __restrict__ dtwb, const float* __restrict__ dtb,
        float* __restrict__ xdbl, float* __restrict__ dts) {
    __shared__ ushort As[64][200];    // stride 200: 2-way banks max
    __shared__ ushort Ws[48][200];
    __shared__ ushort Wd[192][40];
    __shared__ ushort dsh[64][40];

    const int tid  = threadIdx.x;
    const int lane = tid & 63;
    const int wave = tid >> 6;
    const int bm = blockIdx.x * 64;
    const int bk = blockIdx.y;
    const int k  = bk & 3;
    const int frow = lane & 15;
    const int fk   = (lane >> 4) * 8;
    const int orow = (lane >> 4) * 4;
    const int wr = wave * 16;             // wave's 16-row M-tile

    // stage As: 64x192 bf16 (1536 ushort8 slots / 256 threads = 6 each)
#pragma unroll
    for (int i = 0; i < 6; ++i) {
        int idx = tid + i * 256;
        int row = idx / 24, q = idx % 24;
        float4 v = *(const float4*)&xsb[(size_t)(bk * L_SZ + bm + row) * DI + q * 8];
        *(float4*)&As[row][q * 8] = v;
    }
    // stage Ws: 48x192 prepadded (1152 slots)
#pragma unroll
    for (int i = 0; i < 5; ++i) {
        int idx = tid + i * 256;
        if (idx < 1152) {
            int row = idx / 24, q = idx % 24;
            float4 v = *(const float4*)&xpwb[(size_t)(k * 48 + row) * DI + q * 8];
            *(float4*)&Ws[row][q * 8] = v;
        }
    }
    // stage Wd: 192x40 prepadded (960 slots)
#pragma unroll
    for (int i = 0; i < 4; ++i) {
        int idx = tid + i * 256;
        if (idx < 960) {
            int row = idx / 5, q = idx % 5;
            float4 v = *(const float4*)&dtwb[(size_t)(k * DI + row) * 40 + q * 8];
            *(float4*)&Wd[row][q * 8] = v;
        }
    }
    __syncthreads();

    // GEMM1: each wave: 1 M-tile x 3 N-tiles, K=192
    f32x4 acc1[3] = {};
#pragma unroll
    for (int k0 = 0; k0 < 192; k0 += 32) {
        short8 af = *(const short8*)&As[wr + frow][k0 + fk];
#pragma unroll
        for (int ni = 0; ni < 3; ++ni) {
            short8 bv = *(const short8*)&Ws[ni * 16 + frow][k0 + fk];
            acc1[ni] = __builtin_amdgcn_mfma_f32_16x16x32_bf16(af, bv, acc1[ni], 0, 0, 0);
        }
    }

    // epilogue 1: B/C cols -> global; dt-rank cols -> dsh (bf16)
#pragma unroll
    for (int ni = 0; ni < 3; ++ni) {
        int col = ni * 16 + frow;
#pragma unroll
        for (int r = 0; r < 4; ++r) {
            float v = acc1[ni][r];
            int row = wr + orow + r;
            if (col >= RR && col < XD)
                xdbl[(size_t)(bk * L_SZ + bm + row) * XD + col] = v;
            if (ni == 0 && col < RR)
                dsh[row][col] = f2b(v);
        }
    }
    // zero-pad dsh cols 12..31 (read as K up to 32)
    if (tid < 192) {
        int row = tid / 3, which = tid % 3;
        if (which == 0) { ushort z4[4] = {0,0,0,0}; *(double*)&dsh[row][12] = *(double*)z4; }
        else { float4 z = {0,0,0,0}; *(float4*)&dsh[row][which == 1 ? 16 : 24] = z; }
    }
    __syncthreads();

    // GEMM2: A = dsh (64x32), B = Wd (192x32) -> dts (64x192)
    short8 af2 = *(const short8*)&dsh[wr + frow][fk];
#pragma unroll
    for (int ni = 0; ni < 12; ++ni) {
        short8 bv = *(const short8*)&Wd[ni * 16 + frow][fk];
        f32x4 a2 = {};
        a2 = __builtin_amdgcn_mfma_f32_16x16x32_bf16(af2, bv, a2, 0, 0, 0);
        int d = ni * 16 + frow;
        float bias = dtb[k * DI + d];
#pragma unroll
        for (int r = 0; r < 4; ++r) {
            float a = a2[r] + bias;
            float sp = (a > 20.f) ? a : log1pf(__expf(a));
            dts[(size_t)(bk * L_SZ + bm + wr + orow + r) * DI + d] = sp;
        }
    }
}

// ---------------------------------------------------------------------------
// Scan pass A
// ---------------------------------------------------------------------------
__global__ __launch_bounds__(192) void scan_passA(
        const float* __restrict__ dts, const float* __restrict__ xs,
        const float* __restrict__ xdbl, const float* __restrict__ A_logs,
        float* __restrict__ Ebuf, float* __restrict__ Sbuf) {
    int blk = blockIdx.x;
    int bk = blk / NC, ch = blk % NC;
    int d = threadIdx.x, k = bk % KG;
    int l0 = ch * CL;

    __shared__ float bsh[CL][NS];
    for (int t = threadIdx.x; t < CL * NS; t += 192) {
        int l = t / NS, n = t % NS;
        bsh[l][n] = xdbl[(size_t)(bk * L_SZ + l0 + l) * XD + RR + n];
    }
    __syncthreads();

    float Aa[NS], E[NS], S[NS];
    const float* ar = &A_logs[(size_t)(k * DI + d) * NS];
#pragma unroll
    for (int n = 0; n < NS; ++n) { Aa[n] = -__expf(ar[n]); E[n] = 1.f; S[n] = 0.f; }

    for (int l = 0; l < CL; ++l) {
        float dt = dts[(size_t)(bk * L_SZ + l0 + l) * DI + d];
        float u  = xs [(size_t)(bk * L_SZ + l0 + l) * DI + d];
        float du = dt * u;
        float4 b0 = *(const float4*)&bsh[l][0];
        float4 b1 = *(const float4*)&bsh[l][4];
        float4 b2 = *(const float4*)&bsh[l][8];
        float4 b3 = *(const float4*)&bsh[l][12];
        float Bv[NS] = {b0.x,b0.y,b0.z,b0.w, b1.x,b1.y,b1.z,b1.w,
                        b2.x,b2.y,b2.z,b2.w, b3.x,b3.y,b3.z,b3.w};
#pragma unroll
        for (int n = 0; n < NS; ++n) {
            float e = __expf(dt * Aa[n]);
            E[n] *= e;
            S[n] = fmaf(S[n], e, du * Bv[n]);
        }
    }
    float* ep = &Ebuf[(size_t)((bk * NC + ch) * DI + d) * NS];
    float* sp = &Sbuf[(size_t)((bk * NC + ch) * DI + d) * NS];
#pragma unroll
    for (int n = 0; n < NS; ++n) { ep[n] = E[n]; sp[n] = S[n]; }
}

// ---------------------------------------------------------------------------
// Scan pass B: chunk prefix
// ---------------------------------------------------------------------------
__global__ __launch_bounds__(256) void scan_passB(
        const float* __restrict__ Ebuf, const float* __restrict__ Sbuf,
        float* __restrict__ Hstart) {
    int idx = blockIdx.x * 256 + threadIdx.x;     // 8*DI*NS = 24576
    int bk = idx / (DI * NS);
    int dn = idx % (DI * NS);
    float h = 0.f;
    for (int c = 0; c < NC; ++c) {
        size_t off = (size_t)(bk * NC + c) * DI * NS + dn;
        Hstart[off] = h;
        h = Ebuf[off] * h + Sbuf[off];
    }
}

// ---------------------------------------------------------------------------
// Scan pass C: replay chunk, emit y into spatial layout
// ---------------------------------------------------------------------------
__global__ __launch_bounds__(192) void scan_passC(
        const float* __restrict__ dts, const float* __restrict__ xs,
        const float* __restrict__ xdbl, const float* __restrict__ A_logs,
        const float* __restrict__ Hstart, const float* __restrict__ Ds,
        float* __restrict__ ypre) {
    int blk = blockIdx.x;
    int bk = blk / NC, ch = blk % NC;
    int d = threadIdx.x, k = bk % KG, b = bk / KG;
    int l0 = ch * CL;

    __shared__ float bsh[CL][NS];
    __shared__ float csh[CL][NS];
    for (int t = threadIdx.x; t < CL * NS; t += 192) {
        int l = t / NS, n = t % NS;
        const float* row = &xdbl[(size_t)(bk * L_SZ + l0 + l) * XD];
        bsh[l][n] = row[RR + n];
        csh[l][n] = row[RR + NS + n];
    }
    __syncthreads();

    float Aa[NS], h[NS];
    const float* ar = &A_logs[(size_t)(k * DI + d) * NS];
    const float* hp = &Hstart[(size_t)((bk * NC + ch) * DI + d) * NS];
#pragma unroll
    for (int n = 0; n < NS; ++n) { Aa[n] = -__expf(ar[n]); h[n] = hp[n]; }
    float Dd = Ds[k * DI + d];

    for (int l = 0; l < CL; ++l) {
        float dt = dts[(size_t)(bk * L_SZ + l0 + l) * DI + d];
        float u  = xs [(size_t)(bk * L_SZ + l0 + l) * DI + d];
        float du = dt * u;
        float4 b0 = *(const float4*)&bsh[l][0];
        float4 b1 = *(const float4*)&bsh[l][4];
        float4 b2 = *(const float4*)&bsh[l][8];
        float4 b3 = *(const float4*)&bsh[l][12];
        float Bv[NS] = {b0.x,b0.y,b0.z,b0.w, b1.x,b1.y,b1.z,b1.w,
                        b2.x,b2.y,b2.z,b2.w, b3.x,b3.y,b3.z,b3.w};
        float4 c0 = *(const float4*)&csh[l][0];
        float4 c1 = *(const float4*)&csh[l][4];
        float4 c2 = *(const float4*)&csh[l][8];
        float4 c3 = *(const float4*)&csh[l][12];
        float Cv[NS] = {c0.x,c0.y,c0.z,c0.w, c1.x,c1.y,c1.z,c1.w,
                        c2.x,c2.y,c2.z,c2.w, c3.x,c3.y,c3.z,c3.w};
        float p[NS];
#pragma unroll
        for (int n = 0; n < NS; ++n) {
            float e = __expf(dt * Aa[n]);
            h[n] = fmaf(h[n], e, du * Bv[n]);
            p[n] = h[n] * Cv[n];
        }
#pragma unroll
        for (int s = 8; s >= 1; s >>= 1)
#pragma unroll
            for (int n = 0; n < 8; ++n)
                if (n < s) p[n] = p[n] + p[n + s];
        float y = fmaf(Dd, u, p[0]);

        int lg = l0 + l;
        int pos;
        if      (k == 0) pos = lg;
        else if (k == 1) pos = (lg % H_SZ) * W_SZ + (lg / H_SZ);
        else if (k == 2) pos = L_SZ - 1 - lg;
        else { int j = L_SZ - 1 - lg; pos = (j % H_SZ) * W_SZ + (j / H_SZ); }
        ypre[(size_t)(b * L_SZ + pos) * CIN + k * DI + d] = y;
    }
}

// ---------------------------------------------------------------------------
// LayerNorm over CIN=768; read fp32, write bf16 (for out-proj MFMA).
// ---------------------------------------------------------------------------
__global__ __launch_bounds__(256) void layernorm_bf16(
        const float* __restrict__ y, ushort* __restrict__ yb,
        const float* __restrict__ w, const float* __restrict__ bg) {
    int wave = threadIdx.x >> 6, lane = threadIdx.x & 63;
    int tok = blockIdx.x * 4 + wave;
    const float* row = &y[(size_t)tok * CIN];
    ushort* rowo = &yb[(size_t)tok * CIN];
    float v[12];
    float s = 0.f;
#pragma unroll
    for (int i = 0; i < 12; ++i) { v[i] = row[lane + i * 64]; s += v[i]; }
#pragma unroll
    for (int off = 32; off >= 1; off >>= 1) s += __shfl_xor(s, off, 64);
    float mu = s * (1.f / CIN);
    float s2 = 0.f;
#pragma unroll
    for (int i = 0; i < 12; ++i) { float t = v[i] - mu; s2 += t * t; }
#pragma unroll
    for (int off = 32; off >= 1; off >>= 1) s2 += __shfl_xor(s2, off, 64);
    float rstd = rsqrtf(s2 * (1.f / CIN) + 1e-5f);
#pragma unroll
    for (int i = 0; i < 12; ++i)
        rowo[lane + i * 64] =
            f2b((v[i] - mu) * rstd * w[lane + i * 64] + bg[lane + i * 64]);
}

// ---------------------------------------------------------------------------
extern "C" void kernel_launch(void* const* d_in, const int* in_sizes, int n_in,
                              void* d_out, int out_size, void* d_ws, size_t ws_size,
                              hipStream_t stream) {
    const float* x    = (const float*)d_in[0];
    const float* inw  = (const float*)d_in[1];
    const float* cw   = (const float*)d_in[2];
    const float* cb   = (const float*)d_in[3];
    const float* xpw  = (const float*)d_in[4];
    const float* dtw  = (const float*)d_in[5];
    const float* dtb  = (const float*)d_in[6];
    const float* alog = (const float*)d_in[7];
    const float* Dsp  = (const float*)d_in[8];
    const float* lnw  = (const float*)d_in[9];
    const float* lnb  = (const float*)d_in[10];
    const float* outw = (const float*)d_in[11];
    float* out = (float*)d_out;

    float* ws = (float*)d_ws;
    const size_t SZ_BIG = (size_t)MTOK * CIN;            // 3,538,944
    float* xz    = ws;
    float* xs    = xz  + SZ_BIG;
    float* dts   = xs  + SZ_BIG;
    float* xdbl  = dts + SZ_BIG;                         // (8,L,44)
    float* Ebuf  = xdbl + (size_t)8 * L_SZ * XD;         // 1.77M floats
    float* Sbuf  = Ebuf + (size_t)8 * NC * DI * NS;
    float* Hst   = Sbuf + (size_t)8 * NC * DI * NS;
    ushort* outwb = (ushort*)(Hst + (size_t)8 * NC * DI * NS);
    ushort* xpwb  = outwb + (size_t)CIN * 384;           // 4*48*192
    ushort* dtwb  = xpwb + (size_t)4 * 48 * 192;         // 4*192*40
    // lifetime overlays (strictly sequential producer/consumer):
    ushort* xb     = (ushort*)dts;    // cast -> in-proj GEMM
    ushort* inwb   = (ushort*)Ebuf;   // cast -> in-proj GEMM
    ushort* xsb    = (ushort*)Ebuf;   // conv -> xproj (clobbers dead inwb; dead before scanA)
    ushort* ypre_b = (ushort*)Sbuf;   // LN -> out-proj (Sbuf dead after passB; exact fit)
    float*  ypre   = xz;              // passC out (xz dead after conv)

    // 0. casts (x, in_proj_w, out_proj_w, xpw padded, dtw padded)
    cast_bf16_all<<<(NX8 + 2 * NW8 + NP8 + ND8) / 256, 256, 0, stream>>>(
        x, inw, outw, xpw, dtw, xb, inwb, outwb, xpwb, dtwb);
    // 1. in-proj GEMM (bf16 MFMA)
    gemm_bf16_nt<<<dim3(CIN / 128, MTOK / 128), 256, 0, stream>>>(xb, inwb, xz, MTOK, CIN, 384);
    // 2. depthwise conv + SiLU + scatter (fp32 + bf16)
    conv_silu_scatter<<<(B_SZ * H_SZ * W_SZ * CIN) / 256, 256, 0, stream>>>(xz, cw, cb, xs, xsb);
    // 3+4. fused MFMA x-projection + dt-projection
    xproj_dt_mfma<<<dim3(L_SZ / 64, 8), 256, 0, stream>>>(xsb, xpwb, dtwb, dtb, xdbl, dts);
    // 5-7. chunked selective scan
    scan_passA<<<8 * NC, 192, 0, stream>>>(dts, xs, xdbl, alog, Ebuf, Sbuf);
    scan_passB<<<(8 * DI * NS) / 256, 256, 0, stream>>>(Ebuf, Sbuf, Hst);
    scan_passC<<<8 * NC, 192, 0, stream>>>(dts, xs, xdbl, alog, Hst, Dsp, ypre);
    // 8. LayerNorm: fp32 in, bf16 out
    layernorm_bf16<<<MTOK / 4, 256, 0, stream>>>(ypre, ypre_b, lnw, lnb);
    // 9. out-proj GEMM (bf16 MFMA)
    gemm_bf16_nt<<<dim3(384 / 128, MTOK / 128), 256, 0, stream>>>(ypre_b, outwb, out, MTOK, 384, CIN);
}

// Round 5
// 250.095 us; speedup vs baseline: 1.5923x; 1.0139x over previous
//
#include <hip/hip_runtime.h>
#include <hip/hip_bf16.h>

#define B_SZ   2
#define H_SZ   48
#define W_SZ   48
#define L_SZ   2304          // H*W
#define CIN    768           // C_INNER
#define KG     4
#define DI     192           // D_IN (channels per direction)
#define NS     16            // N_STATE
#define RR     12            // R_RANK
#define XD     44            // RR + 2*NS
#define MTOK   4608          // B*L
#define CL     16            // scan chunk length
#define NC     144           // L / CL

typedef __attribute__((ext_vector_type(8))) short short8;
typedef __attribute__((ext_vector_type(4))) float f32x4;

__device__ inline ushort f2b(float f) {
    uint u = __builtin_bit_cast(uint, f);
    u = (u + 0x7FFF + ((u >> 16) & 1)) >> 16;   // RNE to bf16
    return (ushort)u;
}
__device__ inline float b2f(ushort b) {
    uint u = ((uint)b) << 16;
    return __builtin_bit_cast(float, u);
}

// ---------------------------------------------------------------------------
// bf16 MFMA GEMM:  C[M,N](fp32) = A[M,K](bf16) * Bw[N,K](bf16)^T
// 128x128 tile, BK=32, 256 threads (4 waves in 2x2), 4x4 frags of 16x16x32.
// ---------------------------------------------------------------------------
__global__ __launch_bounds__(256) void gemm_bf16_nt(
        const ushort* __restrict__ A, const ushort* __restrict__ Bw,
        float* __restrict__ C, int M, int N, int K) {
    __shared__ ushort As[128][40];
    __shared__ ushort Bs[128][40];
    const int tid  = threadIdx.x;
    const int lane = tid & 63;
    const int wave = tid >> 6;
    const int wr = (wave >> 1) * 64;
    const int wc = (wave & 1) * 64;
    const int bm = blockIdx.y * 128, bn = blockIdx.x * 128;
    const int lrow = tid >> 1;
    const int lcol = (tid & 1) * 16;
    const int frow = lane & 15;
    const int fk   = (lane >> 4) * 8;

    f32x4 acc[4][4] = {};

    for (int k0 = 0; k0 < K; k0 += 32) {
        const ushort* ap = &A [(size_t)(bm + lrow) * K + k0 + lcol];
        const ushort* bp = &Bw[(size_t)(bn + lrow) * K + k0 + lcol];
        float4 a0 = *(const float4*)ap;
        float4 a1 = *(const float4*)(ap + 8);
        float4 b0 = *(const float4*)bp;
        float4 b1 = *(const float4*)(bp + 8);
        __syncthreads();
        *(float4*)&As[lrow][lcol]     = a0;
        *(float4*)&As[lrow][lcol + 8] = a1;
        *(float4*)&Bs[lrow][lcol]     = b0;
        *(float4*)&Bs[lrow][lcol + 8] = b1;
        __syncthreads();

        short8 af[4], bf[4];
#pragma unroll
        for (int i = 0; i < 4; ++i) {
            af[i] = *(const short8*)&As[wr + i * 16 + frow][fk];
            bf[i] = *(const short8*)&Bs[wc + i * 16 + frow][fk];
        }
#pragma unroll
        for (int mi = 0; mi < 4; ++mi)
#pragma unroll
            for (int ni = 0; ni < 4; ++ni)
                acc[mi][ni] = __builtin_amdgcn_mfma_f32_16x16x32_bf16(
                                  af[mi], bf[ni], acc[mi][ni], 0, 0, 0);
    }

#pragma unroll
    for (int mi = 0; mi < 4; ++mi) {
        int rbase = bm + wr + mi * 16 + (lane >> 4) * 4;
#pragma unroll
        for (int ni = 0; ni < 4; ++ni) {
            int col = bn + wc + ni * 16 + (lane & 15);
#pragma unroll
            for (int r = 0; r < 4; ++r)
                C[(size_t)(rbase + r) * N + col] = acc[mi][ni][r];
        }
    }
}

// ---------------------------------------------------------------------------
// Cast kernel: x, in_proj_w, out_proj_w -> bf16; xpw -> padded bf16 [4][48][192];
// dtw -> padded bf16 [4][192][40] (cols 12..39 zero).
// ---------------------------------------------------------------------------
#define NX8 (MTOK * 384 / 8)      // 221184
#define NW8 (CIN * 384 / 8)       // 36864
#define NP8 (4 * 48 * 192 / 8)    // 4608
#define ND8 (4 * DI * 40 / 8)     // 3840
__global__ __launch_bounds__(256) void cast_bf16_all(
        const float* __restrict__ x, const float* __restrict__ w1,
        const float* __restrict__ w2, const float* __restrict__ xpw,
        const float* __restrict__ dtw,
        ushort* __restrict__ xb, ushort* __restrict__ w1b,
        ushort* __restrict__ w2b, ushort* __restrict__ xpwb,
        ushort* __restrict__ dtwb) {
    int t = blockIdx.x * 256 + threadIdx.x;
    if (t < NX8 + 2 * NW8) {
        const float* src; ushort* dst; int off;
        if (t < NX8)            { src = x;  dst = xb;  off = t; }
        else if (t < NX8 + NW8) { src = w1; dst = w1b; off = t - NX8; }
        else                    { src = w2; dst = w2b; off = t - NX8 - NW8; }
        float4 v0 = ((const float4*)src)[off * 2];
        float4 v1 = ((const float4*)src)[off * 2 + 1];
        ushort u[8] = { f2b(v0.x), f2b(v0.y), f2b(v0.z), f2b(v0.w),
                        f2b(v1.x), f2b(v1.y), f2b(v1.z), f2b(v1.w) };
        *(float4*)&dst[off * 8] = *(float4*)u;
    } else if (t < NX8 + 2 * NW8 + NP8) {
        int e0 = (t - NX8 - 2 * NW8) * 8;
        int kk = e0 / (48 * 192);
        int rem = e0 % (48 * 192);
        int c = rem / 192, col = rem % 192;
        ushort u[8] = {0,0,0,0,0,0,0,0};
        if (c < XD) {
            const float* src = &xpw[((size_t)kk * XD + c) * 192 + col];
            float4 v0 = *(const float4*)src;
            float4 v1 = *(const float4*)(src + 4);
            u[0]=f2b(v0.x); u[1]=f2b(v0.y); u[2]=f2b(v0.z); u[3]=f2b(v0.w);
            u[4]=f2b(v1.x); u[5]=f2b(v1.y); u[6]=f2b(v1.z); u[7]=f2b(v1.w);
        }
        *(float4*)&xpwb[e0] = *(float4*)u;
    } else if (t < NX8 + 2 * NW8 + NP8 + ND8) {
        int e0 = (t - NX8 - 2 * NW8 - NP8) * 8;
        int row = e0 / 40, c0 = e0 % 40;
        ushort u[8] = {0,0,0,0,0,0,0,0};
        if (c0 < RR) {
#pragma unroll
            for (int j = 0; j < 8; ++j) {
                int col = c0 + j;
                if (col < RR) u[j] = f2b(dtw[(size_t)row * RR + col]);
            }
        }
        *(float4*)&dtwb[e0] = *(float4*)u;
    }
}

// ---------------------------------------------------------------------------
// Depthwise 3x3 conv (SAME) + bias + SiLU on NHWC input; scatter into the
// four scan orders xsb[b][k][l'][d] (bf16 only).
// ---------------------------------------------------------------------------
__global__ __launch_bounds__(256) void conv_silu_scatter(
        const float* __restrict__ xz, const float* __restrict__ cw,
        const float* __restrict__ cb, ushort* __restrict__ xsb) {
    int idx = blockIdx.x * 256 + threadIdx.x;
    int c = idx % CIN;
    int rest = idx / CIN;
    int w = rest % W_SZ; rest /= W_SZ;
    int h = rest % H_SZ;
    int b = rest / H_SZ;

    float acc = cb[c];
#pragma unroll
    for (int dh = -1; dh <= 1; ++dh) {
        int hh = h + dh;
        if (hh < 0 || hh >= H_SZ) continue;
#pragma unroll
        for (int dw = -1; dw <= 1; ++dw) {
            int ww = w + dw;
            if (ww < 0 || ww >= W_SZ) continue;
            acc += xz[(size_t)((b * H_SZ + hh) * W_SZ + ww) * CIN + c]
                 * cw[c * 9 + (dh + 1) * 3 + (dw + 1)];
        }
    }
    float s = acc / (1.f + __expf(-acc));   // SiLU

    int k = c / DI, d = c % DI;
    int lrow = h * W_SZ + w;
    int lcol = w * H_SZ + h;
    int l;
    if      (k == 0) l = lrow;
    else if (k == 1) l = lcol;
    else if (k == 2) l = L_SZ - 1 - lrow;
    else             l = L_SZ - 1 - lcol;
    xsb[(size_t)((b * KG + k) * L_SZ + l) * DI + d] = f2b(s);
}

// ---------------------------------------------------------------------------
// MFMA fused x-projection + dt-projection. A-fragments direct from global
// (L2-warm); only weights + dt-intermediate in LDS (39.7 KB -> 4 blocks/CU).
// ---------------------------------------------------------------------------
__global__ __launch_bounds__(256) void xproj_dt_mfma(
        const ushort* __restrict__ xsb, const ushort* __restrict__ xpwb,
        const ushort* __restrict__ dtwb, const float* __restrict__ dtb,
        float* __restrict__ xdbl, float* __restrict__ dts) {
    __shared__ ushort Ws[48][200];
    __shared__ ushort Wd[192][40];
    __shared__ ushort dsh[64][40];

    const int tid  = threadIdx.x;
    const int lane = tid & 63;
    const int wave = tid >> 6;
    const int bm = blockIdx.x * 64;
    const int bk = blockIdx.y;
    const int k  = bk & 3;
    const int frow = lane & 15;
    const int fk   = (lane >> 4) * 8;
    const int orow = (lane >> 4) * 4;
    const int wr = wave * 16;

    // stage Ws: 48x192 prepadded (1152 float4 slots)
#pragma unroll
    for (int i = 0; i < 5; ++i) {
        int idx = tid + i * 256;
        if (idx < 1152) {
            int row = idx / 24, q = idx % 24;
            float4 v = *(const float4*)&xpwb[(size_t)(k * 48 + row) * DI + q * 8];
            *(float4*)&Ws[row][q * 8] = v;
        }
    }
    // stage Wd: 192x40 prepadded (960 slots)
#pragma unroll
    for (int i = 0; i < 4; ++i) {
        int idx = tid + i * 256;
        if (idx < 960) {
            int row = idx / 5, q = idx % 5;
            float4 v = *(const float4*)&dtwb[(size_t)(k * DI + row) * 40 + q * 8];
            *(float4*)&Wd[row][q * 8] = v;
        }
    }
    __syncthreads();

    // GEMM1: A-frags from global, K=192 fully unrolled (6 loads hoisted)
    f32x4 acc1[3] = {};
    const ushort* arow = &xsb[(size_t)(bk * L_SZ + bm + wr + frow) * DI];
#pragma unroll
    for (int k0 = 0; k0 < 192; k0 += 32) {
        short8 af = *(const short8*)&arow[k0 + fk];
#pragma unroll
        for (int ni = 0; ni < 3; ++ni) {
            short8 bv = *(const short8*)&Ws[ni * 16 + frow][k0 + fk];
            acc1[ni] = __builtin_amdgcn_mfma_f32_16x16x32_bf16(af, bv, acc1[ni], 0, 0, 0);
        }
    }

    // epilogue 1: B/C cols -> global; dt-rank cols -> dsh (bf16)
#pragma unroll
    for (int ni = 0; ni < 3; ++ni) {
        int col = ni * 16 + frow;
#pragma unroll
        for (int r = 0; r < 4; ++r) {
            float v = acc1[ni][r];
            int row = wr + orow + r;
            if (col >= RR && col < XD)
                xdbl[(size_t)(bk * L_SZ + bm + row) * XD + col] = v;
            if (ni == 0 && col < RR)
                dsh[row][col] = f2b(v);
        }
    }
    // zero-pad dsh cols 12..31
    if (tid < 192) {
        int row = tid / 3, which = tid % 3;
        if (which == 0) { ushort z4[4] = {0,0,0,0}; *(double*)&dsh[row][12] = *(double*)z4; }
        else { float4 z = {0,0,0,0}; *(float4*)&dsh[row][which == 1 ? 16 : 24] = z; }
    }
    __syncthreads();

    // GEMM2: A = dsh (64x32), B = Wd (192x32) -> softplus -> dts (64x192)
    short8 af2 = *(const short8*)&dsh[wr + frow][fk];
#pragma unroll
    for (int ni = 0; ni < 12; ++ni) {
        short8 bv = *(const short8*)&Wd[ni * 16 + frow][fk];
        f32x4 a2 = {};
        a2 = __builtin_amdgcn_mfma_f32_16x16x32_bf16(af2, bv, a2, 0, 0, 0);
        int d = ni * 16 + frow;
        float bias = dtb[k * DI + d];
#pragma unroll
        for (int r = 0; r < 4; ++r) {
            float a = a2[r] + bias;
            float sp = (a > 20.f) ? a : log1pf(__expf(a));
            dts[(size_t)(bk * L_SZ + bm + wr + orow + r) * DI + d] = sp;
        }
    }
}

// ---------------------------------------------------------------------------
// Scan pass A: per (bk, chunk, d, n) E = prod(e_l), S = local scan. CL=16.
// ---------------------------------------------------------------------------
__global__ __launch_bounds__(192) void scan_passA(
        const float* __restrict__ dts, const ushort* __restrict__ xsb,
        const float* __restrict__ xdbl, const float* __restrict__ A_logs,
        float* __restrict__ Ebuf, float* __restrict__ Sbuf) {
    int blk = blockIdx.x;
    int bk = blk / NC, ch = blk % NC;
    int d = threadIdx.x, k = bk % KG;
    int l0 = ch * CL;

    __shared__ float bsh[CL][NS];
    for (int t = threadIdx.x; t < CL * NS; t += 192) {
        int l = t / NS, n = t % NS;
        bsh[l][n] = xdbl[(size_t)(bk * L_SZ + l0 + l) * XD + RR + n];
    }
    __syncthreads();

    float Aa[NS], E[NS], S[NS];
    const float* ar = &A_logs[(size_t)(k * DI + d) * NS];
#pragma unroll
    for (int n = 0; n < NS; ++n) { Aa[n] = -__expf(ar[n]); E[n] = 1.f; S[n] = 0.f; }

#pragma unroll 4
    for (int l = 0; l < CL; ++l) {
        float dt = dts[(size_t)(bk * L_SZ + l0 + l) * DI + d];
        float u  = b2f(xsb[(size_t)(bk * L_SZ + l0 + l) * DI + d]);
        float du = dt * u;
        float4 b0 = *(const float4*)&bsh[l][0];
        float4 b1 = *(const float4*)&bsh[l][4];
        float4 b2 = *(const float4*)&bsh[l][8];
        float4 b3 = *(const float4*)&bsh[l][12];
        float Bv[NS] = {b0.x,b0.y,b0.z,b0.w, b1.x,b1.y,b1.z,b1.w,
                        b2.x,b2.y,b2.z,b2.w, b3.x,b3.y,b3.z,b3.w};
#pragma unroll
        for (int n = 0; n < NS; ++n) {
            float e = __expf(dt * Aa[n]);
            E[n] *= e;
            S[n] = fmaf(S[n], e, du * Bv[n]);
        }
    }
    float* ep = &Ebuf[(size_t)((bk * NC + ch) * DI + d) * NS];
    float* sp = &Sbuf[(size_t)((bk * NC + ch) * DI + d) * NS];
#pragma unroll
    for (int n = 0; n < NS; ++n) { ep[n] = E[n]; sp[n] = S[n]; }
}

// ---------------------------------------------------------------------------
// Scan pass B: chunk prefix over NC=144 chunks.
// ---------------------------------------------------------------------------
__global__ __launch_bounds__(256) void scan_passB(
        const float* __restrict__ Ebuf, const float* __restrict__ Sbuf,
        float* __restrict__ Hstart) {
    int idx = blockIdx.x * 256 + threadIdx.x;     // 8*DI*NS = 24576
    int bk = idx / (DI * NS);
    int dn = idx % (DI * NS);
    float h = 0.f;
    for (int c = 0; c < NC; ++c) {
        size_t off = (size_t)(bk * NC + c) * DI * NS + dn;
        Hstart[off] = h;
        h = Ebuf[off] * h + Sbuf[off];
    }
}

// ---------------------------------------------------------------------------
// Scan pass C: replay chunk with true h_start, emit y. CL=16.
// ---------------------------------------------------------------------------
__global__ __launch_bounds__(192) void scan_passC(
        const float* __restrict__ dts, const ushort* __restrict__ xsb,
        const float* __restrict__ xdbl, const float* __restrict__ A_logs,
        const float* __restrict__ Hstart, const float* __restrict__ Ds,
        float* __restrict__ ypre) {
    int blk = blockIdx.x;
    int bk = blk / NC, ch = blk % NC;
    int d = threadIdx.x, k = bk % KG, b = bk / KG;
    int l0 = ch * CL;

    __shared__ float bsh[CL][NS];
    __shared__ float csh[CL][NS];
    for (int t = threadIdx.x; t < CL * NS; t += 192) {
        int l = t / NS, n = t % NS;
        const float* row = &xdbl[(size_t)(bk * L_SZ + l0 + l) * XD];
        bsh[l][n] = row[RR + n];
        csh[l][n] = row[RR + NS + n];
    }
    __syncthreads();

    float Aa[NS], h[NS];
    const float* ar = &A_logs[(size_t)(k * DI + d) * NS];
    const float* hp = &Hstart[(size_t)((bk * NC + ch) * DI + d) * NS];
#pragma unroll
    for (int n = 0; n < NS; ++n) { Aa[n] = -__expf(ar[n]); h[n] = hp[n]; }
    float Dd = Ds[k * DI + d];

#pragma unroll 4
    for (int l = 0; l < CL; ++l) {
        float dt = dts[(size_t)(bk * L_SZ + l0 + l) * DI + d];
        float u  = b2f(xsb[(size_t)(bk * L_SZ + l0 + l) * DI + d]);
        float du = dt * u;
        float4 b0 = *(const float4*)&bsh[l][0];
        float4 b1 = *(const float4*)&bsh[l][4];
        float4 b2 = *(const float4*)&bsh[l][8];
        float4 b3 = *(const float4*)&bsh[l][12];
        float Bv[NS] = {b0.x,b0.y,b0.z,b0.w, b1.x,b1.y,b1.z,b1.w,
                        b2.x,b2.y,b2.z,b2.w, b3.x,b3.y,b3.z,b3.w};
        float4 c0 = *(const float4*)&csh[l][0];
        float4 c1 = *(const float4*)&csh[l][4];
        float4 c2 = *(const float4*)&csh[l][8];
        float4 c3 = *(const float4*)&csh[l][12];
        float Cv[NS] = {c0.x,c0.y,c0.z,c0.w, c1.x,c1.y,c1.z,c1.w,
                        c2.x,c2.y,c2.z,c2.w, c3.x,c3.y,c3.z,c3.w};
        float p[NS];
#pragma unroll
        for (int n = 0; n < NS; ++n) {
            float e = __expf(dt * Aa[n]);
            h[n] = fmaf(h[n], e, du * Bv[n]);
            p[n] = h[n] * Cv[n];
        }
#pragma unroll
        for (int s = 8; s >= 1; s >>= 1)
#pragma unroll
            for (int n = 0; n < 8; ++n)
                if (n < s) p[n] = p[n] + p[n + s];
        float y = fmaf(Dd, u, p[0]);

        int lg = l0 + l;
        int pos;
        if      (k == 0) pos = lg;
        else if (k == 1) pos = (lg % H_SZ) * W_SZ + (lg / H_SZ);
        else if (k == 2) pos = L_SZ - 1 - lg;
        else { int j = L_SZ - 1 - lg; pos = (j % H_SZ) * W_SZ + (j / H_SZ); }
        ypre[(size_t)(b * L_SZ + pos) * CIN + k * DI + d] = y;
    }
}

// ---------------------------------------------------------------------------
// LayerNorm over CIN=768; read fp32, write bf16 (for out-proj MFMA).
// ---------------------------------------------------------------------------
__global__ __launch_bounds__(256) void layernorm_bf16(
        const float* __restrict__ y, ushort* __restrict__ yb,
        const float* __restrict__ w, const float* __restrict__ bg) {
    int wave = threadIdx.x >> 6, lane = threadIdx.x & 63;
    int tok = blockIdx.x * 4 + wave;
    const float* row = &y[(size_t)tok * CIN];
    ushort* rowo = &yb[(size_t)tok * CIN];
    float v[12];
    float s = 0.f;
#pragma unroll
    for (int i = 0; i < 12; ++i) { v[i] = row[lane + i * 64]; s += v[i]; }
#pragma unroll
    for (int off = 32; off >= 1; off >>= 1) s += __shfl_xor(s, off, 64);
    float mu = s * (1.f / CIN);
    float s2 = 0.f;
#pragma unroll
    for (int i = 0; i < 12; ++i) { float t = v[i] - mu; s2 += t * t; }
#pragma unroll
    for (int off = 32; off >= 1; off >>= 1) s2 += __shfl_xor(s2, off, 64);
    float rstd = rsqrtf(s2 * (1.f / CIN) + 1e-5f);
#pragma unroll
    for (int i = 0; i < 12; ++i)
        rowo[lane + i * 64] =
            f2b((v[i] - mu) * rstd * w[lane + i * 64] + bg[lane + i * 64]);
}

// ---------------------------------------------------------------------------
extern "C" void kernel_launch(void* const* d_in, const int* in_sizes, int n_in,
                              void* d_out, int out_size, void* d_ws, size_t ws_size,
                              hipStream_t stream) {
    const float* x    = (const float*)d_in[0];
    const float* inw  = (const float*)d_in[1];
    const float* cw   = (const float*)d_in[2];
    const float* cb   = (const float*)d_in[3];
    const float* xpw  = (const float*)d_in[4];
    const float* dtw  = (const float*)d_in[5];
    const float* dtb  = (const float*)d_in[6];
    const float* alog = (const float*)d_in[7];
    const float* Dsp  = (const float*)d_in[8];
    const float* lnw  = (const float*)d_in[9];
    const float* lnb  = (const float*)d_in[10];
    const float* outw = (const float*)d_in[11];
    float* out = (float*)d_out;

    float* ws = (float*)d_ws;
    const size_t SZ_BIG = (size_t)MTOK * CIN;            // 3,538,944
    float* xz    = ws;                                   // later: ypre
    float* xsbf  = xz  + SZ_BIG;                         // bf16 xs, 1.77M floats
    float* dts   = xsbf + SZ_BIG / 2;
    float* xdbl  = dts + SZ_BIG;                         // (8,L,44)
    float* Ebuf  = xdbl + (size_t)8 * L_SZ * XD;         // (8,NC,192,16) = 3.54M
    float* Sbuf  = Ebuf + (size_t)8 * NC * DI * NS;
    float* Hst   = Sbuf + (size_t)8 * NC * DI * NS;
    ushort* outwb = (ushort*)(Hst + (size_t)8 * NC * DI * NS);
    ushort* xpwb  = outwb + (size_t)CIN * 384;
    ushort* dtwb  = xpwb + (size_t)4 * 48 * 192;
    // lifetime overlays (strictly sequential producer/consumer):
    ushort* xb     = (ushort*)dts;    // cast -> in-proj GEMM (dts written later)
    ushort* inwb   = (ushort*)Ebuf;   // cast -> in-proj GEMM (Ebuf written in scanA)
    ushort* xsb    = (ushort*)xsbf;   // conv -> xproj + scans (own slot)
    ushort* ypre_b = (ushort*)Sbuf;   // LN -> out-proj (Sbuf dead after passB)
    float*  ypre   = xz;              // passC out (xz dead after conv)

    // 0. casts
    cast_bf16_all<<<(NX8 + 2 * NW8 + NP8 + ND8) / 256, 256, 0, stream>>>(
        x, inw, outw, xpw, dtw, xb, inwb, outwb, xpwb, dtwb);
    // 1. in-proj GEMM (bf16 MFMA)
    gemm_bf16_nt<<<dim3(CIN / 128, MTOK / 128), 256, 0, stream>>>(xb, inwb, xz, MTOK, CIN, 384);
    // 2. depthwise conv + SiLU + scatter (bf16 only)
    conv_silu_scatter<<<(B_SZ * H_SZ * W_SZ * CIN) / 256, 256, 0, stream>>>(xz, cw, cb, xsb);
    // 3+4. fused MFMA x-projection + dt-projection
    xproj_dt_mfma<<<dim3(L_SZ / 64, 8), 256, 0, stream>>>(xsb, xpwb, dtwb, dtb, xdbl, dts);
    // 5-7. chunked selective scan (CL=16)
    scan_passA<<<8 * NC, 192, 0, stream>>>(dts, xsb, xdbl, alog, Ebuf, Sbuf);
    scan_passB<<<(8 * DI * NS) / 256, 256, 0, stream>>>(Ebuf, Sbuf, Hst);
    scan_passC<<<8 * NC, 192, 0, stream>>>(dts, xsb, xdbl, alog, Hst, Dsp, ypre);
    // 8. LayerNorm: fp32 in, bf16 out
    layernorm_bf16<<<MTOK / 4, 256, 0, stream>>>(ypre, ypre_b, lnw, lnb);
    // 9. out-proj GEMM (bf16 MFMA)
    gemm_bf16_nt<<<dim3(384 / 128, MTOK / 128), 256, 0, stream>>>(ypre_b, outwb, out, MTOK, 384, CIN);
}

// Round 6
// 241.447 us; speedup vs baseline: 1.6493x; 1.0358x over previous
//
#include <hip/hip_runtime.h>
#include <hip/hip_bf16.h>

#define B_SZ   2
#define H_SZ   48
#define W_SZ   48
#define L_SZ   2304          // H*W
#define CIN    768           // C_INNER
#define KG     4
#define DI     192           // D_IN (channels per direction)
#define NS     16            // N_STATE
#define RR     12            // R_RANK
#define XD     44            // RR + 2*NS
#define MTOK   4608          // B*L
#define CL     32            // scan chunk length
#define NC     72            // L / CL

typedef __attribute__((ext_vector_type(8))) short short8;
typedef __attribute__((ext_vector_type(4))) float f32x4;

__device__ inline ushort f2b(float f) {
    uint u = __builtin_bit_cast(uint, f);
    u = (u + 0x7FFF + ((u >> 16) & 1)) >> 16;   // RNE to bf16
    return (ushort)u;
}
__device__ inline float b2f(ushort b) {
    uint u = ((uint)b) << 16;
    return __builtin_bit_cast(float, u);
}
__device__ inline short8 f2b8(float4 a, float4 b) {
    short8 r;
    r[0] = (short)f2b(a.x); r[1] = (short)f2b(a.y);
    r[2] = (short)f2b(a.z); r[3] = (short)f2b(a.w);
    r[4] = (short)f2b(b.x); r[5] = (short)f2b(b.y);
    r[6] = (short)f2b(b.z); r[7] = (short)f2b(b.w);
    return r;
}

// ---------------------------------------------------------------------------
// MFMA GEMM, TN=64 column tiles:  C[M,N](fp32) = A[M,K] * Bw[N,K]^T
// A is bf16 (ABF=true) or fp32 cast inline (ABF=false); Bw is fp32 cast inline.
// 256 threads = 4 waves stacked on M; MF = TM/64 m-frags, 4 n-frags per wave.
// TM=128: 432 blocks for in-proj; TM=64: 432 blocks for out-proj.
// ---------------------------------------------------------------------------
template<int TM, bool ABF>
__global__ __launch_bounds__(256) void gemm_tn64(
        const void* __restrict__ Av, const float* __restrict__ Bw,
        float* __restrict__ C, int M, int N, int K) {
    __shared__ ushort As[TM][40];
    __shared__ ushort Bs[64][40];
    const int tid  = threadIdx.x;
    const int lane = tid & 63;
    const int wave = tid >> 6;
    constexpr int MF = TM / 64;
    const int wrow = wave * (MF * 16);
    const int bm = blockIdx.y * TM, bn = blockIdx.x * 64;
    const int frow = lane & 15;
    const int fk   = (lane >> 4) * 8;
    const int orow = (lane >> 4) * 4;

    f32x4 acc[MF][4] = {};

    for (int k0 = 0; k0 < K; k0 += 32) {
        // load stage (global, before barrier)
        short8 aval[MF];
#pragma unroll
        for (int i = 0; i < MF; ++i) {
            int idx = tid + i * 256;
            int row = idx >> 2, q = idx & 3;
            if (ABF) {
                aval[i] = *(const short8*)&((const ushort*)Av)[(size_t)(bm + row) * K + k0 + q * 8];
            } else {
                const float* ap = &((const float*)Av)[(size_t)(bm + row) * K + k0 + q * 8];
                aval[i] = f2b8(*(const float4*)ap, *(const float4*)(ap + 4));
            }
        }
        const float* bp = &Bw[(size_t)(bn + (tid >> 2)) * K + k0 + (tid & 3) * 8];
        short8 bval = f2b8(*(const float4*)bp, *(const float4*)(bp + 4));

        __syncthreads();
#pragma unroll
        for (int i = 0; i < MF; ++i) {
            int idx = tid + i * 256;
            *(short8*)&As[idx >> 2][(idx & 3) * 8] = aval[i];
        }
        *(short8*)&Bs[tid >> 2][(tid & 3) * 8] = bval;
        __syncthreads();

        short8 af[MF], bf[4];
#pragma unroll
        for (int mi = 0; mi < MF; ++mi)
            af[mi] = *(const short8*)&As[wrow + mi * 16 + frow][fk];
#pragma unroll
        for (int ni = 0; ni < 4; ++ni)
            bf[ni] = *(const short8*)&Bs[ni * 16 + frow][fk];
#pragma unroll
        for (int mi = 0; mi < MF; ++mi)
#pragma unroll
            for (int ni = 0; ni < 4; ++ni)
                acc[mi][ni] = __builtin_amdgcn_mfma_f32_16x16x32_bf16(
                                  af[mi], bf[ni], acc[mi][ni], 0, 0, 0);
    }

#pragma unroll
    for (int mi = 0; mi < MF; ++mi) {
        int rbase = bm + wrow + mi * 16 + orow;
#pragma unroll
        for (int ni = 0; ni < 4; ++ni) {
            int col = bn + ni * 16 + frow;
#pragma unroll
            for (int r = 0; r < 4; ++r)
                C[(size_t)(rbase + r) * N + col] = acc[mi][ni][r];
        }
    }
}

// ---------------------------------------------------------------------------
// Depthwise 3x3 conv (SAME) + bias + SiLU on NHWC input; scatter into the
// four scan orders xsb[b][k][l'][d] (bf16).
// ---------------------------------------------------------------------------
__global__ __launch_bounds__(256) void conv_silu_scatter(
        const float* __restrict__ xz, const float* __restrict__ cw,
        const float* __restrict__ cb, ushort* __restrict__ xsb) {
    int idx = blockIdx.x * 256 + threadIdx.x;
    int c = idx % CIN;
    int rest = idx / CIN;
    int w = rest % W_SZ; rest /= W_SZ;
    int h = rest % H_SZ;
    int b = rest / H_SZ;

    float acc = cb[c];
#pragma unroll
    for (int dh = -1; dh <= 1; ++dh) {
        int hh = h + dh;
        if (hh < 0 || hh >= H_SZ) continue;
#pragma unroll
        for (int dw = -1; dw <= 1; ++dw) {
            int ww = w + dw;
            if (ww < 0 || ww >= W_SZ) continue;
            acc += xz[(size_t)((b * H_SZ + hh) * W_SZ + ww) * CIN + c]
                 * cw[c * 9 + (dh + 1) * 3 + (dw + 1)];
        }
    }
    float s = acc / (1.f + __expf(-acc));   // SiLU

    int k = c / DI, d = c % DI;
    int lrow = h * W_SZ + w;
    int lcol = w * H_SZ + h;
    int l;
    if      (k == 0) l = lrow;
    else if (k == 1) l = lcol;
    else if (k == 2) l = L_SZ - 1 - lrow;
    else             l = L_SZ - 1 - lcol;
    xsb[(size_t)((b * KG + k) * L_SZ + l) * DI + d] = f2b(s);
}

// ---------------------------------------------------------------------------
// MFMA fused x-projection + dt-projection. 768 threads = 12 waves:
// GEMM1: 4 row-groups x 3 col-groups (64 l-rows x 48 cols, K=192).
// GEMM2: 12 d-groups x 4 row-groups (dt low-rank, K=32 zero-padded).
// Weights (fp32) cast inline into LDS. A-frags direct from global (L2-warm).
// ---------------------------------------------------------------------------
__global__ __launch_bounds__(768) void xproj_dt_mfma(
        const ushort* __restrict__ xsb, const float* __restrict__ xpw,
        const float* __restrict__ dtw, const float* __restrict__ dtb,
        float* __restrict__ xdbl, float* __restrict__ dts) {
    __shared__ ushort Ws[48][200];
    __shared__ ushort Wd[192][40];
    __shared__ ushort dsh[64][40];

    const int tid  = threadIdx.x;
    const int lane = tid & 63;
    const int wave = tid >> 6;        // 0..11
    const int bm = blockIdx.x * 64;
    const int bk = blockIdx.y;
    const int k  = bk & 3;
    const int frow = lane & 15;
    const int fk   = (lane >> 4) * 8;
    const int orow = (lane >> 4) * 4;
    const int rg = wave & 3;          // row group (GEMM1)
    const int cg = wave >> 2;         // col group 0..2 (GEMM1)

    // stage Ws (48x192, inline cast, rows >= 44 zero): 2304 4-col tasks
#pragma unroll
    for (int i = 0; i < 3; ++i) {
        int idx = tid + i * 768;
        int row = idx / 48, g = idx % 48;
        ushort4 u = {0, 0, 0, 0};
        if (row < XD) {
            float4 v = *(const float4*)&xpw[((size_t)(k * XD) + row) * 192 + g * 4];
            u.x = f2b(v.x); u.y = f2b(v.y); u.z = f2b(v.z); u.w = f2b(v.w);
        }
        *(ushort4*)&Ws[row][g * 4] = u;
    }
    // zero Wd (960 float4 slots) + dsh (320 slots)
#pragma unroll
    for (int i = 0; i < 2; ++i) {
        int idx = tid + i * 768;
        if (idx < 960) {
            float4 z = {0.f, 0.f, 0.f, 0.f};
            *(float4*)&Wd[idx / 5][(idx % 5) * 8] = z;
        } else if (idx < 1280) {
            int j = idx - 960;
            float4 z = {0.f, 0.f, 0.f, 0.f};
            *(float4*)&dsh[j / 5][(j % 5) * 8] = z;
        }
    }
    __syncthreads();

    // fill Wd cols 0..11 (inline cast)
#pragma unroll
    for (int i = 0; i < 3; ++i) {
        int idx = tid + i * 768;
        int row = idx / RR, c = idx % RR;
        Wd[row][c] = f2b(dtw[((size_t)(k * DI) + row) * RR + c]);
    }

    // GEMM1: rows rg*16, cols cg*16, K=192
    f32x4 acc1 = {};
    const ushort* arow = &xsb[(size_t)(bk * L_SZ + bm + rg * 16 + frow) * DI];
#pragma unroll
    for (int k0 = 0; k0 < 192; k0 += 32) {
        short8 af = *(const short8*)&arow[k0 + fk];
        short8 bv = *(const short8*)&Ws[cg * 16 + frow][k0 + fk];
        acc1 = __builtin_amdgcn_mfma_f32_16x16x32_bf16(af, bv, acc1, 0, 0, 0);
    }

    // epilogue 1: B/C cols -> xdbl global; dt-rank cols -> dsh (bf16)
    {
        int col = cg * 16 + frow;
#pragma unroll
        for (int r = 0; r < 4; ++r) {
            float v = acc1[r];
            int row = rg * 16 + orow + r;
            if (col >= RR && col < XD)
                xdbl[(size_t)(bk * L_SZ + bm + row) * XD + col] = v;
            if (cg == 0 && col < RR)
                dsh[row][col] = f2b(v);
        }
    }
    __syncthreads();

    // GEMM2: wave = d-group ni (12 groups of 16 d); 4 row-groups each
    {
        int d = wave * 16 + frow;
        short8 bv = *(const short8*)&Wd[d][fk];
        float bias = dtb[k * DI + d];
#pragma unroll
        for (int rg2 = 0; rg2 < 4; ++rg2) {
            short8 af2 = *(const short8*)&dsh[rg2 * 16 + frow][fk];
            f32x4 a2 = {};
            a2 = __builtin_amdgcn_mfma_f32_16x16x32_bf16(af2, bv, a2, 0, 0, 0);
#pragma unroll
            for (int r = 0; r < 4; ++r) {
                float a = a2[r] + bias;
                float sp = (a > 20.f) ? a : log1pf(__expf(a));
                dts[(size_t)(bk * L_SZ + bm + rg2 * 16 + orow + r) * DI + d] = sp;
            }
        }
    }
}

// ---------------------------------------------------------------------------
// Scan pass A: per (bk, chunk, d, n) E = prod(e_l), S = local scan. CL=32.
// ---------------------------------------------------------------------------
__global__ __launch_bounds__(192) void scan_passA(
        const float* __restrict__ dts, const ushort* __restrict__ xsb,
        const float* __restrict__ xdbl, const float* __restrict__ A_logs,
        float* __restrict__ Ebuf, float* __restrict__ Sbuf) {
    int blk = blockIdx.x;
    int bk = blk / NC, ch = blk % NC;
    int d = threadIdx.x, k = bk % KG;
    int l0 = ch * CL;

    __shared__ float bsh[CL][NS];
    for (int t = threadIdx.x; t < CL * NS; t += 192) {
        int l = t / NS, n = t % NS;
        bsh[l][n] = xdbl[(size_t)(bk * L_SZ + l0 + l) * XD + RR + n];
    }
    __syncthreads();

    float Aa[NS], E[NS], S[NS];
    const float* ar = &A_logs[(size_t)(k * DI + d) * NS];
#pragma unroll
    for (int n = 0; n < NS; ++n) { Aa[n] = -__expf(ar[n]); E[n] = 1.f; S[n] = 0.f; }

#pragma unroll 4
    for (int l = 0; l < CL; ++l) {
        float dt = dts[(size_t)(bk * L_SZ + l0 + l) * DI + d];
        float u  = b2f(xsb[(size_t)(bk * L_SZ + l0 + l) * DI + d]);
        float du = dt * u;
        float4 b0 = *(const float4*)&bsh[l][0];
        float4 b1 = *(const float4*)&bsh[l][4];
        float4 b2 = *(const float4*)&bsh[l][8];
        float4 b3 = *(const float4*)&bsh[l][12];
        float Bv[NS] = {b0.x,b0.y,b0.z,b0.w, b1.x,b1.y,b1.z,b1.w,
                        b2.x,b2.y,b2.z,b2.w, b3.x,b3.y,b3.z,b3.w};
#pragma unroll
        for (int n = 0; n < NS; ++n) {
            float e = __expf(dt * Aa[n]);
            E[n] *= e;
            S[n] = fmaf(S[n], e, du * Bv[n]);
        }
    }
    float* ep = &Ebuf[(size_t)((bk * NC + ch) * DI + d) * NS];
    float* sp = &Sbuf[(size_t)((bk * NC + ch) * DI + d) * NS];
#pragma unroll
    for (int n = 0; n < NS; ++n) { ep[n] = E[n]; sp[n] = S[n]; }
}

// ---------------------------------------------------------------------------
// Scan pass B: chunk prefix; one thread per (bk,d,4n) -> float4 chains.
// 6144 threads, prefetched loads.
// ---------------------------------------------------------------------------
__global__ __launch_bounds__(256) void scan_passB(
        const float* __restrict__ Ebuf, const float* __restrict__ Sbuf,
        float* __restrict__ Hstart) {
    int t = blockIdx.x * 256 + threadIdx.x;       // 8*192*4 = 6144
    int bk = t / (DI * 4);
    int dn = (t % (DI * 4)) * 4;                  // d*NS+n, n multiple of 4
    size_t off = (size_t)(bk * NC) * DI * NS + dn;
    const size_t stride = (size_t)DI * NS;

    float4 h = {0.f, 0.f, 0.f, 0.f};
    float4 e = *(const float4*)&Ebuf[off];
    float4 s = *(const float4*)&Sbuf[off];
    for (int c = 0; c < NC; ++c) {
        float4 en, sn;
        if (c + 1 < NC) {
            en = *(const float4*)&Ebuf[off + stride];
            sn = *(const float4*)&Sbuf[off + stride];
        }
        *(float4*)&Hstart[off] = h;
        h.x = fmaf(e.x, h.x, s.x);
        h.y = fmaf(e.y, h.y, s.y);
        h.z = fmaf(e.z, h.z, s.z);
        h.w = fmaf(e.w, h.w, s.w);
        off += stride; e = en; s = sn;
    }
}

// ---------------------------------------------------------------------------
// Scan pass C: replay chunk with true h_start, emit y. CL=32.
// ---------------------------------------------------------------------------
__global__ __launch_bounds__(192) void scan_passC(
        const float* __restrict__ dts, const ushort* __restrict__ xsb,
        const float* __restrict__ xdbl, const float* __restrict__ A_logs,
        const float* __restrict__ Hstart, const float* __restrict__ Ds,
        float* __restrict__ ypre) {
    int blk = blockIdx.x;
    int bk = blk / NC, ch = blk % NC;
    int d = threadIdx.x, k = bk % KG, b = bk / KG;
    int l0 = ch * CL;

    __shared__ float bsh[CL][NS];
    __shared__ float csh[CL][NS];
    for (int t = threadIdx.x; t < CL * NS; t += 192) {
        int l = t / NS, n = t % NS;
        const float* row = &xdbl[(size_t)(bk * L_SZ + l0 + l) * XD];
        bsh[l][n] = row[RR + n];
        csh[l][n] = row[RR + NS + n];
    }
    __syncthreads();

    float Aa[NS], h[NS];
    const float* ar = &A_logs[(size_t)(k * DI + d) * NS];
    const float* hp = &Hstart[(size_t)((bk * NC + ch) * DI + d) * NS];
#pragma unroll
    for (int n = 0; n < NS; ++n) { Aa[n] = -__expf(ar[n]); h[n] = hp[n]; }
    float Dd = Ds[k * DI + d];

#pragma unroll 4
    for (int l = 0; l < CL; ++l) {
        float dt = dts[(size_t)(bk * L_SZ + l0 + l) * DI + d];
        float u  = b2f(xsb[(size_t)(bk * L_SZ + l0 + l) * DI + d]);
        float du = dt * u;
        float4 b0 = *(const float4*)&bsh[l][0];
        float4 b1 = *(const float4*)&bsh[l][4];
        float4 b2 = *(const float4*)&bsh[l][8];
        float4 b3 = *(const float4*)&bsh[l][12];
        float Bv[NS] = {b0.x,b0.y,b0.z,b0.w, b1.x,b1.y,b1.z,b1.w,
                        b2.x,b2.y,b2.z,b2.w, b3.x,b3.y,b3.z,b3.w};
        float4 c0 = *(const float4*)&csh[l][0];
        float4 c1 = *(const float4*)&csh[l][4];
        float4 c2 = *(const float4*)&csh[l][8];
        float4 c3 = *(const float4*)&csh[l][12];
        float Cv[NS] = {c0.x,c0.y,c0.z,c0.w, c1.x,c1.y,c1.z,c1.w,
                        c2.x,c2.y,c2.z,c2.w, c3.x,c3.y,c3.z,c3.w};
        float p[NS];
#pragma unroll
        for (int n = 0; n < NS; ++n) {
            float e = __expf(dt * Aa[n]);
            h[n] = fmaf(h[n], e, du * Bv[n]);
            p[n] = h[n] * Cv[n];
        }
#pragma unroll
        for (int s = 8; s >= 1; s >>= 1)
#pragma unroll
            for (int n = 0; n < 8; ++n)
                if (n < s) p[n] = p[n] + p[n + s];
        float y = fmaf(Dd, u, p[0]);

        int lg = l0 + l;
        int pos;
        if      (k == 0) pos = lg;
        else if (k == 1) pos = (lg % H_SZ) * W_SZ + (lg / H_SZ);
        else if (k == 2) pos = L_SZ - 1 - lg;
        else { int j = L_SZ - 1 - lg; pos = (j % H_SZ) * W_SZ + (j / H_SZ); }
        ypre[(size_t)(b * L_SZ + pos) * CIN + k * DI + d] = y;
    }
}

// ---------------------------------------------------------------------------
// LayerNorm over CIN=768; read fp32, write bf16 (for out-proj MFMA).
// ---------------------------------------------------------------------------
__global__ __launch_bounds__(256) void layernorm_bf16(
        const float* __restrict__ y, ushort* __restrict__ yb,
        const float* __restrict__ w, const float* __restrict__ bg) {
    int wave = threadIdx.x >> 6, lane = threadIdx.x & 63;
    int tok = blockIdx.x * 4 + wave;
    const float* row = &y[(size_t)tok * CIN];
    ushort* rowo = &yb[(size_t)tok * CIN];
    float v[12];
    float s = 0.f;
#pragma unroll
    for (int i = 0; i < 12; ++i) { v[i] = row[lane + i * 64]; s += v[i]; }
#pragma unroll
    for (int off = 32; off >= 1; off >>= 1) s += __shfl_xor(s, off, 64);
    float mu = s * (1.f / CIN);
    float s2 = 0.f;
#pragma unroll
    for (int i = 0; i < 12; ++i) { float t = v[i] - mu; s2 += t * t; }
#pragma unroll
    for (int off = 32; off >= 1; off >>= 1) s2 += __shfl_xor(s2, off, 64);
    float rstd = rsqrtf(s2 * (1.f / CIN) + 1e-5f);
#pragma unroll
    for (int i = 0; i < 12; ++i)
        rowo[lane + i * 64] =
            f2b((v[i] - mu) * rstd * w[lane + i * 64] + bg[lane + i * 64]);
}

// ---------------------------------------------------------------------------
extern "C" void kernel_launch(void* const* d_in, const int* in_sizes, int n_in,
                              void* d_out, int out_size, void* d_ws, size_t ws_size,
                              hipStream_t stream) {
    const float* x    = (const float*)d_in[0];
    const float* inw  = (const float*)d_in[1];
    const float* cw   = (const float*)d_in[2];
    const float* cb   = (const float*)d_in[3];
    const float* xpw  = (const float*)d_in[4];
    const float* dtw  = (const float*)d_in[5];
    const float* dtb  = (const float*)d_in[6];
    const float* alog = (const float*)d_in[7];
    const float* Dsp  = (const float*)d_in[8];
    const float* lnw  = (const float*)d_in[9];
    const float* lnb  = (const float*)d_in[10];
    const float* outw = (const float*)d_in[11];
    float* out = (float*)d_out;

    float* ws = (float*)d_ws;
    const size_t SZ_BIG = (size_t)MTOK * CIN;            // 3,538,944
    float* xz    = ws;                                   // later: ypre
    float* xsbf  = xz  + SZ_BIG;                         // bf16 xs (1.77M floats)
    float* dts   = xsbf + SZ_BIG / 2;
    float* xdbl  = dts + SZ_BIG;                         // (8,L,44)
    float* Ebuf  = xdbl + (size_t)8 * L_SZ * XD;         // (8,72,192,16) = 1.77M
    float* Sbuf  = Ebuf + (size_t)8 * NC * DI * NS;
    float* Hst   = Sbuf + (size_t)8 * NC * DI * NS;
    // lifetime overlays:
    ushort* xsb    = (ushort*)xsbf;   // conv -> xproj + scans
    ushort* ypre_b = (ushort*)Sbuf;   // LN -> out-proj (Sbuf dead after passB)
    float*  ypre   = xz;              // passC out (xz dead after conv)

    // 1. in-proj GEMM (bf16 MFMA, inline fp32->bf16 cast)
    gemm_tn64<128, false><<<dim3(CIN / 64, MTOK / 128), 256, 0, stream>>>(
        x, inw, xz, MTOK, CIN, 384);
    // 2. depthwise conv + SiLU + scatter (bf16)
    conv_silu_scatter<<<(B_SZ * H_SZ * W_SZ * CIN) / 256, 256, 0, stream>>>(xz, cw, cb, xsb);
    // 3. fused MFMA x-projection + dt-projection (12 waves/block)
    xproj_dt_mfma<<<dim3(L_SZ / 64, 8), 768, 0, stream>>>(xsb, xpw, dtw, dtb, xdbl, dts);
    // 4-6. chunked selective scan (CL=32)
    scan_passA<<<8 * NC, 192, 0, stream>>>(dts, xsb, xdbl, alog, Ebuf, Sbuf);
    scan_passB<<<(8 * DI * 4) / 256, 256, 0, stream>>>(Ebuf, Sbuf, Hst);
    scan_passC<<<8 * NC, 192, 0, stream>>>(dts, xsb, xdbl, alog, Hst, Dsp, ypre);
    // 7. LayerNorm: fp32 in, bf16 out
    layernorm_bf16<<<MTOK / 4, 256, 0, stream>>>(ypre, ypre_b, lnw, lnb);
    // 8. out-proj GEMM (bf16 A, inline-cast B)
    gemm_tn64<64, true><<<dim3(384 / 64, MTOK / 64), 256, 0, stream>>>(
        ypre_b, outw, out, MTOK, 384, CIN);
}